// Round 8
// baseline (6321.413 us; speedup 1.0000x reference)
//
#include <hip/hip_runtime.h>
#include <hip/hip_bf16.h>

// ---------------------------------------------------------------------------
// Problem constants
// ---------------------------------------------------------------------------
#define NA 5000           // atoms
#define NE 40000          // edges
// DA=128, DV=96, DD=64, NL=8, L=2

// ---------------------------------------------------------------------------
// Workspace layout (float indices)
// ---------------------------------------------------------------------------
static const int POFF[13] = {0, 131072, 229376, 294912, 368640, 466944, 516096,
                             589824, 663552, 696320, 761856, 811008, 843776};
#define A_OFF    892928          // a  [2][NA][128] fp32
#define V_OFF    2172928         // v  [2][NA][288] fp32
#define D_OFF    5052928         // d  [2][NA][576] fp32
#define PHI_OFF  10812928        // [NE][12] fp32
#define PSIA_OFF 11292928        // bf16 [NE][256]
#define PSIV_OFF 16412928        // bf16 [NE][576]
#define PSID_OFF 27932928        // bf16 [NE][1152]
#define INT_OFF  50972928
// int region (indices into (int*)(ws + INT_OFF))
#define ICNT  0        // [5000]
#define ICUR  5000     // [5000]
#define SCNT  10000    // [5000]
#define SCUR  15000    // [5000]
#define IOFF  20000    // [5001]
#define SOFF  25008    // [5001]
#define IEIDX 30016    // [NE]
#define ISLOT 70016    // [NE]
#define SPERM 110016   // [NE]

// output layout (floats)
#define OUT_V 640000
#define OUT_D 2080000

// transposed-MLP-weight scratch at the HEAD of d_out (free until gather).
#define WT1 0          // [128][256]
#define WT2 32768      // [256][256]
#define WT3 98304      // [256][128]
#define WTD 131072     // [128][128]
#define VT1 147456     // [96][192]
#define VT2 165888     // [192][192]
#define VT3 202752     // [192][96]
#define VTD 221184     // [96][96]   -> ends 230400

#define OFF_000 POFF[0]
#define OFF_110 POFF[1]
#define OFF_220 POFF[2]
#define OFF_011 POFF[3]
#define OFF_101 POFF[4]
#define OFF_121 POFF[5]
#define OFF_211 POFF[6]
#define OFF_111 POFF[7]
#define OFF_022 POFF[8]
#define OFF_202 POFF[9]
#define OFF_112 POFF[10]
#define OFF_222 POFF[11]
#define OFF_212 POFF[12]

__device__ __forceinline__ float dot4f(float4 a, float4 b) {
  return a.x*b.x + a.y*b.y + a.z*b.z + a.w*b.w;
}
__device__ __forceinline__ float lrelu(float x) { return x > 0.f ? x : 0.1f*x; }
__device__ __forceinline__ float bf2f(unsigned short u) {
  union { unsigned int i; float f; } x; x.i = ((unsigned int)u) << 16; return x.f;
}
__device__ __forceinline__ unsigned short f2bf(float f) {
  union { unsigned int i; float f; } x; x.f = f;
  unsigned int r = x.i + 0x7FFFu + ((x.i >> 16) & 1u);
  return (unsigned short)(r >> 16);
}

struct P13 { const float* p[13]; };
struct P8  { const float* p[8]; };

// ---------------------------------------------------------------------------
// Fused P transpose: all 13 tensors [O][8][C] -> [C][O][8] in one launch.
// ---------------------------------------------------------------------------
__global__ __launch_bounds__(256) void transP_all_kernel(P13 ps, float* __restrict__ Pt)
{
  static const int Od[13] = {128,128,128, 96, 96, 96, 96, 96, 64, 64, 64, 64, 64};
  static const int Cd[13] = {128, 96, 64, 96,128, 64, 96, 96, 64,128, 96, 64, 96};
  static const int POF[13] = {0, 131072, 229376, 294912, 368640, 466944, 516096,
                              589824, 663552, 696320, 761856, 811008, 843776};
  static const int CUM[14] = {0,16384,28672,36864,46080,58368,64512,73728,
                              82944,87040,95232,101376,105472,111616};
  int idx = blockIdx.x * 256 + threadIdx.x;
  if (idx >= 111616) return;
  int i = 0;
  while (idx >= CUM[i+1]) ++i;
  const int r = idx - CUM[i];
  const int O = Od[i], C = Cd[i];
  const int o = r / C, c = r % C;
  const float* src = ps.p[i];
  float* dst = Pt + POF[i];
#pragma unroll
  for (int k = 0; k < 8; ++k)
    dst[((size_t)c * O + o) * 8 + k] = src[((size_t)o * 8 + k) * C + c];
}

// ---------------------------------------------------------------------------
// Fused MLP-weight transpose: 8 matrices [R][C] -> [C][R], packed at CUM[i].
// ---------------------------------------------------------------------------
__global__ __launch_bounds__(256) void transW_all_kernel(P8 ps, float* __restrict__ ot)
{
  static const int R[8]   = {256,256,128,128,192,192, 96, 96};
  static const int C[8]   = {128,256,256,128, 96,192,192, 96};
  static const int CUM[9] = {0,32768,98304,131072,147456,165888,202752,221184,230400};
  int idx = blockIdx.x * 256 + threadIdx.x;
  if (idx >= 230400) return;
  int i = 0;
  while (idx >= CUM[i+1]) ++i;
  const int r = idx - CUM[i];
  const int rr = r / C[i], cc = r % C[i];
  ot[(size_t)CUM[i] + (size_t)cc * R[i] + rr] = ps.p[i][r];
}

// ---------------------------------------------------------------------------
// Counting sorts (merged where dependency-free)
// ---------------------------------------------------------------------------
__global__ __launch_bounds__(256) void hist2_kernel(
    const int* __restrict__ dstk, const int* __restrict__ srck,
    int* __restrict__ cntd, int* __restrict__ cnts)
{
  int e = blockIdx.x * 256 + threadIdx.x;
  if (e < NE) { atomicAdd(&cntd[dstk[e]], 1); atomicAdd(&cnts[srck[e]], 1); }
}

__global__ __launch_bounds__(256) void scan2_kernel(
    const int* __restrict__ cnt0, int* __restrict__ off0,
    const int* __restrict__ cnt1, int* __restrict__ off1)
{
  const int* cnt = (blockIdx.x == 0) ? cnt0 : cnt1;
  int* off       = (blockIdx.x == 0) ? off0 : off1;
  __shared__ int part[256];
  const int t = threadIdx.x;
  int loc[20]; int s = 0;
#pragma unroll
  for (int i = 0; i < 20; ++i) {
    int idx = t * 20 + i;
    int v = (idx < NA) ? cnt[idx] : 0;
    loc[i] = v; s += v;
  }
  part[t] = s; __syncthreads();
  for (int ofs = 1; ofs < 256; ofs <<= 1) {
    int v = (t >= ofs) ? part[t - ofs] : 0;
    __syncthreads();
    part[t] += v;
    __syncthreads();
  }
  int run = part[t] - s;   // exclusive prefix
#pragma unroll
  for (int i = 0; i < 20; ++i) {
    int idx = t * 20 + i;
    if (idx < NA) off[idx] = run;
    run += loc[i];
  }
  if (t == 255) off[NA] = run;
}

__global__ __launch_bounds__(256) void sort_scatter_kernel(
    const int* __restrict__ dst, const int* __restrict__ off,
    int* __restrict__ cur, int* __restrict__ eidx, int* __restrict__ islot)
{
  int e = blockIdx.x * 256 + threadIdx.x;
  if (e >= NE) return;
  int d = dst[e];
  int pos = off[d] + atomicAdd(&cur[d], 1);
  eidx[pos] = e;
  islot[e] = pos;
}

// ssort + phi fused (both depend only on sort_scatter outputs)
__global__ __launch_bounds__(256) void ssort_phi_kernel(
    const int* __restrict__ src, const int* __restrict__ islot,
    const int* __restrict__ soff, int* __restrict__ scur, int* __restrict__ sperm,
    const int* __restrict__ eidx, const float* __restrict__ r_ij, float* __restrict__ phi)
{
  const int B = (NE + 255) / 256;
  if ((int)blockIdx.x < B) {
    int e = blockIdx.x * 256 + threadIdx.x;
    if (e >= NE) return;
    int s = src[e];
    int pos = soff[s] + atomicAdd(&scur[s], 1);
    sperm[pos] = islot[e];
  } else {
    int p = (blockIdx.x - B) * 256 + threadIdx.x;
    if (p >= NE) return;
    int e = eidx[p];
    const float rx = r_ij[e*3+0], ry = r_ij[e*3+1], rz = r_ij[e*3+2];
    const float r2 = rx*rx + ry*ry + rz*rz;
    const float r = sqrtf(r2 + 1e-12f);
#pragma unroll
    for (int k = 0; k < 8; ++k) {
      const float z = 7.f*r - (float)k;
      phi[(size_t)p*12 + k] = expf(-0.5f*z*z);
    }
    const float nn = sqrtf(49.f*r2 + 1e-12f);
    const float sc = (2.f / (1.f + expf(-nn)) - 1.f) / nn;
    phi[(size_t)p*12 + 8]  = 7.f*rx*sc;
    phi[(size_t)p*12 + 9]  = 7.f*ry*sc;
    phi[(size_t)p*12 + 10] = 7.f*rz*sc;
    phi[(size_t)p*12 + 11] = 0.f;
  }
}

// ---------------------------------------------------------------------------
// Input projection (per atom)
// ---------------------------------------------------------------------------
__global__ __launch_bounds__(256) void proj_in_kernel(
    const float* __restrict__ x_a, const float* __restrict__ x_v, const float* __restrict__ x_d,
    const float* __restrict__ Wa, const float* __restrict__ Wv, const float* __restrict__ Wd,
    float* __restrict__ a_ws, float* __restrict__ v_ws, float* __restrict__ d_ws)
{
  __shared__ float xs[992];
  const int n = blockIdx.x, t = threadIdx.x;
  for (int q = t; q < 128; q += 256) xs[q]       = x_a[(size_t)n*128 + q];
  for (int q = t; q < 288; q += 256) xs[128 + q] = x_v[(size_t)n*288 + q];
  for (int q = t; q < 576; q += 256) xs[416 + q] = x_d[(size_t)n*576 + q];
  __syncthreads();
  {
    const float* W = &Wa[(size_t)t * 128];
    float acc = 0.f;
    for (int c = 0; c < 128; c += 4) acc += dot4f(*(const float4*)&W[c], *(const float4*)&xs[c]);
    int l = t >> 7, o = t & 127;
    a_ws[((size_t)l*NA + n)*128 + o] = acc;
  }
  if (t < 192) {
    const float* W = &Wv[(size_t)t * 96];
    float a0 = 0.f, a1 = 0.f, a2 = 0.f;
    for (int c = 0; c < 96; ++c) {
      float w = W[c]; const float* x = &xs[128 + c*3];
      a0 = fmaf(w, x[0], a0); a1 = fmaf(w, x[1], a1); a2 = fmaf(w, x[2], a2);
    }
    int l = t / 96, o = t % 96;
    float* dstp = &v_ws[(((size_t)l*NA + n)*96 + o)*3];
    dstp[0] = a0; dstp[1] = a1; dstp[2] = a2;
  }
  if (t < 128) {
    const float* W = &Wd[(size_t)t * 64];
    float acc[9] = {0,0,0,0,0,0,0,0,0};
    for (int c = 0; c < 64; ++c) {
      float w = W[c]; const float* x = &xs[416 + c*9];
#pragma unroll
      for (int j = 0; j < 9; ++j) acc[j] = fmaf(w, x[j], acc[j]);
    }
    int l = t >> 6, o = t & 63;
    float* dstp = &d_ws[(((size_t)l*NA + n)*64 + o)*9];
#pragma unroll
    for (int j = 0; j < 9; ++j) dstp[j] = acc[j];
  }
}

// ---------------------------------------------------------------------------
// Z helpers.  Pt layout [C][O][8].
// ---------------------------------------------------------------------------
template<int O, int C, int NMU>
__device__ __forceinline__ void zcompute(const float* __restrict__ Pt,
    const float* __restrict__ xl, int o, float z[8][NMU])
{
#pragma unroll
  for (int k = 0; k < 8; ++k)
#pragma unroll
    for (int m = 0; m < NMU; ++m) z[k][m] = 0.f;
  const float* p = Pt + o * 8;
#pragma unroll 2
  for (int c = 0; c < C; ++c, p += O*8) {
    const float4 pa = *(const float4*)p;
    const float4 pb = *(const float4*)(p + 4);
#pragma unroll
    for (int m = 0; m < NMU; ++m) {
      const float xv = xl[c * NMU + m];
      z[0][m] = fmaf(pa.x, xv, z[0][m]);
      z[1][m] = fmaf(pa.y, xv, z[1][m]);
      z[2][m] = fmaf(pa.z, xv, z[2][m]);
      z[3][m] = fmaf(pa.w, xv, z[3][m]);
      z[4][m] = fmaf(pb.x, xv, z[4][m]);
      z[5][m] = fmaf(pb.y, xv, z[5][m]);
      z[6][m] = fmaf(pb.z, xv, z[6][m]);
      z[7][m] = fmaf(pb.w, xv, z[7][m]);
    }
  }
}

// half-k variant, generic NMU: z[4][NMU] for k range [kh*4, kh*4+4)
template<int O, int C, int NMU>
__device__ __forceinline__ void zcompute_k4n(const float* __restrict__ Pt,
    const float* __restrict__ xl, int o, int kh, float z[4][NMU])
{
#pragma unroll
  for (int k = 0; k < 4; ++k)
#pragma unroll
    for (int m = 0; m < NMU; ++m) z[k][m] = 0.f;
  const float* p = Pt + o * 8 + kh * 4;
#pragma unroll 2
  for (int c = 0; c < C; ++c, p += O*8) {
    const float4 pa = *(const float4*)p;
#pragma unroll
    for (int m = 0; m < NMU; ++m) {
      const float xv = xl[c*NMU + m];
      z[0][m] = fmaf(pa.x, xv, z[0][m]);
      z[1][m] = fmaf(pa.y, xv, z[1][m]);
      z[2][m] = fmaf(pa.z, xv, z[2][m]);
      z[3][m] = fmaf(pa.w, xv, z[3][m]);
    }
  }
}

template<int NMU>
__device__ __forceinline__ float kdot(const float z[8][NMU], int m, const float* rr) {
  float s = z[0][m] * rr[0];
#pragma unroll
  for (int k = 1; k < 8; ++k) s = fmaf(z[k][m], rr[k], s);
  return s;
}
template<int NMU>
__device__ __forceinline__ float kdot4n(const float z[4][NMU], int m, const float* rr) {
  float s = z[0][m] * rr[0];
#pragma unroll
  for (int k = 1; k < 4; ++k) s = fmaf(z[k][m], rr[k], s);
  return s;
}

// shared feature layout (floats), SINGLE atom, both l:
//   XA [l][128]=256 | XV [l][288]=576 | XD [l][576]=1152  -> 1984
#define F1_XA 0
#define F1_XV 256
#define F1_XD 832
#define F1_TOT 1984

template<int NT>
__device__ __forceinline__ void load_features1(float* sm, int t, int n,
    const float* __restrict__ a_ws, const float* __restrict__ v_ws, const float* __restrict__ d_ws)
{
  for (int q = t; q < 256; q += NT)
    sm[F1_XA + q] = a_ws[((size_t)(q>>7)*NA + n)*128 + (q & 127)];
  for (int q = t; q < 576; q += NT)
    sm[F1_XV + q] = v_ws[((size_t)(q/288)*NA + n)*288 + (q % 288)];
  for (int q = t; q < 1152; q += NT)
    sm[F1_XD + q] = d_ws[((size_t)(q/576)*NA + n)*576 + (q % 576)];
}

// ---------------------------------------------------------------------------
// FUSED message pass: grid 3*NA, 256 thr.  type = blockIdx%3.
// A: 256 thr (o x l), window 16.
// V: 192 active thr (o x l), window 12 (idle wave barrier-safe).
// D: 256 thr = o(64) x l(2) x kh(2) -- k-parallel z (all waves active),
//    psi accumulated via LDS atomicAdd (2-way max contention), window 6.
// ---------------------------------------------------------------------------
__global__ __launch_bounds__(256, 3) void pass_fused_kernel(
    const int* __restrict__ off, const float* __restrict__ phi,
    const float* __restrict__ Pt,
    const float* __restrict__ a_ws, const float* __restrict__ v_ws, const float* __restrict__ d_ws,
    unsigned short* __restrict__ psiA, unsigned short* __restrict__ psiV,
    unsigned short* __restrict__ psiD)
{
  __shared__ float sm[9040];   // max(a:6272, v:9040, d:8968) floats = 36160 B
  const int b = blockIdx.x;
  const int type = b % 3;
  const int n = b / 3;
  const int t = threadIdx.x;
  const int off0 = off[n], off1 = off[n + 1];
  const int d = off1 - off0;
  if (d == 0) return;   // uniform across block: no thread has hit a barrier

  load_features1<256>(sm, t, n, a_ws, v_ws, d_ws);   // all 256 threads help

  if (type == 0) {
    // ---------------- pass A: 256 thr, window 16 ----------------
    const int o = t & 127, l = t >> 7;
    const float* xa = &sm[F1_XA + l*128];
    const float* xv = &sm[F1_XV + l*288];
    const float* xd = &sm[F1_XD + l*576];
    float* sphi = &sm[F1_TOT];            // 192
    float* psis = &sm[F1_TOT + 192];      // [16][256]

    const int nw = (d + 15) >> 4;
    for (int w = 0; w < nw; ++w) {
      const int b0 = w * 16;
      __syncthreads();
      if (t < 192) {
        const int s = t / 12, f = t % 12;
        sphi[t] = (b0 + s < d) ? phi[(size_t)(off0 + b0 + s)*12 + f] : 0.f;
      }
      __syncthreads();

      {
        float z[8][1];
        zcompute<128,128,1>(Pt + OFF_000, xa, o, z);
#pragma unroll
        for (int e = 0; e < 16; ++e)
          psis[e*256 + t] = kdot<1>(z, 0, &sphi[e*12]);
      }
      {
        float z[8][3];
        zcompute<128,96,3>(Pt + OFF_110, xv, o, z);
#pragma unroll
        for (int e = 0; e < 16; ++e) {
          const float* ph = &sphi[e*12];
          psis[e*256 + t] += ph[8]*kdot<3>(z,0,ph) + ph[9]*kdot<3>(z,1,ph) + ph[10]*kdot<3>(z,2,ph);
        }
      }
#pragma unroll
      for (int kh = 0; kh < 2; ++kh) {
        float z[4][9];
        zcompute_k4n<128,64,9>(Pt + OFF_220, xd, o, kh, z);
#pragma unroll
        for (int e = 0; e < 16; ++e) {
          const float* ph = &sphi[e*12];
          const float* rr = ph + kh*4;
          float s[9];
#pragma unroll
          for (int m = 0; m < 9; ++m) s[m] = kdot4n<9>(z, m, rr);
          const float q0 = ph[8], q1 = ph[9], q2 = ph[10];
          psis[e*256 + t] += q0*(q0*s[0] + q1*s[1] + q2*s[2])
                           + q1*(q0*s[3] + q1*s[4] + q2*s[5])
                           + q2*(q0*s[6] + q1*s[7] + q2*s[8]);
        }
      }
#pragma unroll
      for (int e = 0; e < 16; ++e)
        if (b0 + e < d) psiA[(size_t)(off0 + b0 + e)*256 + t] = f2bf(psis[e*256 + t]);
    }
  } else if (type == 1) {
    // ---------------- pass V: 192 active thr, window 12 ----------------
    const bool act = (t < 192);
    const int o = t % 96, l = (t / 96) & 1;   // clamped for surplus lanes
    const float* xa = &sm[F1_XA + l*128];
    const float* xv = &sm[F1_XV + l*288];
    const float* xd = &sm[F1_XD + l*576];
    float* sphi = &sm[F1_TOT];            // 144
    float* psis = &sm[F1_TOT + 144];      // [12][3][192]

    const int nw = (d + 11) / 12;
    for (int w = 0; w < nw; ++w) {
      const int b0 = w * 12;
      __syncthreads();
      if (t < 144) {
        const int s = t / 12, f = t % 12;
        sphi[t] = (b0 + s < d) ? phi[(size_t)(off0 + b0 + s)*12 + f] : 0.f;
      }
      __syncthreads();

      if (act) {
        {
          float z[8][3];
          zcompute<96,96,3>(Pt + OFF_011, xv, o, z);
#pragma unroll
          for (int e = 0; e < 12; ++e) {
            const float* ph = &sphi[e*12];
            float* pb = &psis[e*576 + t];
            pb[0]   = kdot<3>(z,0,ph);
            pb[192] = kdot<3>(z,1,ph);
            pb[384] = kdot<3>(z,2,ph);
          }
        }
        {
          float z[8][1];
          zcompute<96,128,1>(Pt + OFF_101, xa, o, z);
#pragma unroll
          for (int e = 0; e < 12; ++e) {
            const float* ph = &sphi[e*12];
            const float s0 = kdot<1>(z,0,ph);
            float* pb = &psis[e*576 + t];
            pb[0] += ph[8]*s0; pb[192] += ph[9]*s0; pb[384] += ph[10]*s0;
          }
        }
#pragma unroll
        for (int kh = 0; kh < 2; ++kh) {
          float z[4][9];
          zcompute_k4n<96,64,9>(Pt + OFF_121, xd, o, kh, z);
#pragma unroll
          for (int e = 0; e < 12; ++e) {
            const float* ph = &sphi[e*12];
            const float* rr = ph + kh*4;
            float s[9];
#pragma unroll
            for (int m = 0; m < 9; ++m) s[m] = kdot4n<9>(z, m, rr);
            const float q0 = ph[8], q1 = ph[9], q2 = ph[10];
            float* pb = &psis[e*576 + t];
            pb[0]   += q0*s[0] + q1*s[1] + q2*s[2];
            pb[192] += q0*s[3] + q1*s[4] + q2*s[5];
            pb[384] += q0*s[6] + q1*s[7] + q2*s[8];
          }
        }
        {
          float z[8][3];
          zcompute<96,96,3>(Pt + OFF_211, xv, o, z);
#pragma unroll
          for (int e = 0; e < 12; ++e) {
            const float* ph = &sphi[e*12];
            const float tt = ph[8]*kdot<3>(z,0,ph) + ph[9]*kdot<3>(z,1,ph) + ph[10]*kdot<3>(z,2,ph);
            float* pb = &psis[e*576 + t];
            pb[0] += ph[8]*tt; pb[192] += ph[9]*tt; pb[384] += ph[10]*tt;
          }
        }
        {
          float z[8][3];
          zcompute<96,96,3>(Pt + OFF_111, xv, o, z);
#pragma unroll
          for (int e = 0; e < 12; ++e) {
            const float* ph = &sphi[e*12];
            const float s0 = kdot<3>(z,0,ph), s1 = kdot<3>(z,1,ph), s2 = kdot<3>(z,2,ph);
            const float q0 = ph[8], q1 = ph[9], q2 = ph[10];
            float* pb = &psis[e*576 + t];
            pb[0]   += q1*s2 - q2*s1;
            pb[192] += q2*s0 - q0*s2;
            pb[384] += q0*s1 - q1*s0;
          }
        }
#pragma unroll
        for (int e = 0; e < 12; ++e) {
          if (b0 + e < d) {
            const size_t bb = (size_t)(off0 + b0 + e)*576 + l*288 + o*3;
            const float* pb = &psis[e*576 + t];
            psiV[bb+0] = f2bf(pb[0]); psiV[bb+1] = f2bf(pb[192]); psiV[bb+2] = f2bf(pb[384]);
          }
        }
      }
    }
  } else {
    // ---------------- pass D: 256 thr, o x l x kh, window 6 ----------------
    // All contractions are linear in the k-sum: kh=0 handles k 0-3,
    // kh=1 handles k 4-7; halves combine via LDS atomicAdd.
    const int o = t & 63, l = (t >> 6) & 1, kh = t >> 7;
    const int tl = l*64 + o;
    const float* xa = &sm[F1_XA + l*128];
    const float* xv = &sm[F1_XV + l*288];
    const float* xd = &sm[F1_XD + l*576];
    float* sphi = &sm[F1_TOT];            // 72
    float* psis = &sm[F1_TOT + 72];       // [6][128][9]

    const int nw = (d + 5) / 6;
    for (int w = 0; w < nw; ++w) {
      const int b0 = w * 6;
      __syncthreads();                      // prev write-out complete
      for (int q = t; q < 6912; q += 256) psis[q] = 0.f;
      if (t < 72) {
        const int s = t / 12, f = t % 12;
        sphi[t] = (b0 + s < d) ? phi[(size_t)(off0 + b0 + s)*12 + f] : 0.f;
      }
      __syncthreads();                      // zeros + phi visible

      { // 022
        float z[4][9];
        zcompute_k4n<64,64,9>(Pt + OFF_022, xd, o, kh, z);
#pragma unroll
        for (int e = 0; e < 6; ++e) {
          const float* rr = &sphi[e*12] + kh*4;
          float* pb = &psis[(e*128 + tl)*9];
#pragma unroll
          for (int m = 0; m < 9; ++m) atomicAdd(&pb[m], kdot4n<9>(z, m, rr));
        }
      }
      { // 202
        float z[4][1];
        zcompute_k4n<64,128,1>(Pt + OFF_202, xa, o, kh, z);
#pragma unroll
        for (int e = 0; e < 6; ++e) {
          const float* ph = &sphi[e*12];
          const float s0 = kdot4n<1>(z, 0, ph + kh*4);
          const float q0 = ph[8], q1 = ph[9], q2 = ph[10];
          float* pb = &psis[(e*128 + tl)*9];
          atomicAdd(&pb[0], q0*q0*s0); atomicAdd(&pb[1], q0*q1*s0); atomicAdd(&pb[2], q0*q2*s0);
          atomicAdd(&pb[3], q1*q0*s0); atomicAdd(&pb[4], q1*q1*s0); atomicAdd(&pb[5], q1*q2*s0);
          atomicAdd(&pb[6], q2*q0*s0); atomicAdd(&pb[7], q2*q1*s0); atomicAdd(&pb[8], q2*q2*s0);
        }
      }
      { // 112
        float z[4][3];
        zcompute_k4n<64,96,3>(Pt + OFF_112, xv, o, kh, z);
#pragma unroll
        for (int e = 0; e < 6; ++e) {
          const float* ph = &sphi[e*12];
          const float* rr = ph + kh*4;
          const float s0 = kdot4n<3>(z,0,rr), s1 = kdot4n<3>(z,1,rr), s2 = kdot4n<3>(z,2,rr);
          const float q0 = ph[8], q1 = ph[9], q2 = ph[10];
          float* pb = &psis[(e*128 + tl)*9];
          atomicAdd(&pb[0], q0*s0); atomicAdd(&pb[1], q0*s1); atomicAdd(&pb[2], q0*s2);
          atomicAdd(&pb[3], q1*s0); atomicAdd(&pb[4], q1*s1); atomicAdd(&pb[5], q1*s2);
          atomicAdd(&pb[6], q2*s0); atomicAdd(&pb[7], q2*s1); atomicAdd(&pb[8], q2*s2);
        }
      }
      { // 222
        float z[4][9];
        zcompute_k4n<64,64,9>(Pt + OFF_222, xd, o, kh, z);
#pragma unroll
        for (int e = 0; e < 6; ++e) {
          const float* ph = &sphi[e*12];
          const float* rr = ph + kh*4;
          float s[9];
#pragma unroll
          for (int m = 0; m < 9; ++m) s[m] = kdot4n<9>(z, m, rr);
          const float q0 = ph[8], q1 = ph[9], q2 = ph[10];
          const float u0 = q0*s[0] + q1*s[3] + q2*s[6];
          const float u1 = q0*s[1] + q1*s[4] + q2*s[7];
          const float u2 = q0*s[2] + q1*s[5] + q2*s[8];
          float* pb = &psis[(e*128 + tl)*9];
          atomicAdd(&pb[0], q0*u0); atomicAdd(&pb[1], q0*u1); atomicAdd(&pb[2], q0*u2);
          atomicAdd(&pb[3], q1*u0); atomicAdd(&pb[4], q1*u1); atomicAdd(&pb[5], q1*u2);
          atomicAdd(&pb[6], q2*u0); atomicAdd(&pb[7], q2*u1); atomicAdd(&pb[8], q2*u2);
        }
      }
      { // 212
        float z[4][3];
        zcompute_k4n<64,96,3>(Pt + OFF_212, xv, o, kh, z);
#pragma unroll
        for (int e = 0; e < 6; ++e) {
          const float* ph = &sphi[e*12];
          const float* rr = ph + kh*4;
          const float s0 = kdot4n<3>(z,0,rr), s1 = kdot4n<3>(z,1,rr), s2 = kdot4n<3>(z,2,rr);
          const float q0 = ph[8], q1 = ph[9], q2 = ph[10];
          const float c0 = q1*s2 - q2*s1;
          const float c1 = q2*s0 - q0*s2;
          const float c2 = q0*s1 - q1*s0;
          float* pb = &psis[(e*128 + tl)*9];
          atomicAdd(&pb[0], c0*q0); atomicAdd(&pb[1], c0*q1); atomicAdd(&pb[2], c0*q2);
          atomicAdd(&pb[3], c1*q0); atomicAdd(&pb[4], c1*q1); atomicAdd(&pb[5], c1*q2);
          atomicAdd(&pb[6], c2*q0); atomicAdd(&pb[7], c2*q1); atomicAdd(&pb[8], c2*q2);
        }
      }
      __syncthreads();                      // all contributions landed
      // write-out: kh=0 -> e 0..2, kh=1 -> e 3..5
#pragma unroll
      for (int ee = 0; ee < 3; ++ee) {
        const int e = kh*3 + ee;
        if (b0 + e < d) {
          const float* pb = &psis[(e*128 + tl)*9];
          unsigned short* bp = &psiD[(size_t)(off0 + b0 + e)*1152 + tl*9];
#pragma unroll
          for (int j = 0; j < 9; ++j) bp[j] = f2bf(pb[j]);
        }
      }
    }
  }
}

// ---------------------------------------------------------------------------
// FUSED edge MLPs: grid 15000, 256 thr.  b%3==0 -> mlp_a (5000 blocks,
// 16 combos); else -> mlp_v (10000 blocks, 8 combos, 192 active thr).
// NO early returns: barriers at block scope, work guarded by `act`.
// ---------------------------------------------------------------------------
__global__ __launch_bounds__(256, 3) void mlp_fused_kernel(
    unsigned short* __restrict__ psiA, unsigned short* __restrict__ psiV,
    const float* __restrict__ Wdt,
    const float* __restrict__ W1t, const float* __restrict__ b1,
    const float* __restrict__ W2t, const float* __restrict__ b2,
    const float* __restrict__ W3t, const float* __restrict__ b3,
    const float* __restrict__ Vdt, const float* __restrict__ V1t,
    const float* __restrict__ V2t, const float* __restrict__ V3t)
{
  __shared__ float sm[11520];   // max(a:10240, v:11520) floats = 46080 B
  const int b = blockIdx.x;
  const int t = threadIdx.x;

  if (b % 3 == 0) {
    // ---------------- mlp_a: 16 combos ----------------
    const int cbase = (b / 3) * 16;
    float* PA = sm;            // [16][128]
    float* H1 = sm + 2048;     // [16][256]
    float* H2 = sm + 6144;     // [16][256]

    for (int q = t; q < 2048; q += 256)
      PA[q] = bf2f(psiA[(size_t)cbase*128 + q]);
    __syncthreads();
    {
      const int p0 = (t & 63) * 4, j0 = (t >> 6) * 4;
      float acc[4][4];
#pragma unroll
      for (int r = 0; r < 4; ++r)
#pragma unroll
        for (int j = 0; j < 4; ++j) acc[r][j] = 0.f;
      for (int c = 0; c < 128; c += 4) {
        float4 wv[4];
#pragma unroll
        for (int cc = 0; cc < 4; ++cc) wv[cc] = *(const float4*)&W1t[(size_t)(c+cc)*256 + p0];
#pragma unroll
        for (int j = 0; j < 4; ++j) {
          const float4 x = *(const float4*)&PA[(j0+j)*128 + c];
          acc[0][j] += wv[0].x*x.x + wv[1].x*x.y + wv[2].x*x.z + wv[3].x*x.w;
          acc[1][j] += wv[0].y*x.x + wv[1].y*x.y + wv[2].y*x.z + wv[3].y*x.w;
          acc[2][j] += wv[0].z*x.x + wv[1].z*x.y + wv[2].z*x.z + wv[3].z*x.w;
          acc[3][j] += wv[0].w*x.x + wv[1].w*x.y + wv[2].w*x.z + wv[3].w*x.w;
        }
      }
      const float bb0 = b1[p0], bb1 = b1[p0+1], bb2 = b1[p0+2], bb3 = b1[p0+3];
#pragma unroll
      for (int j = 0; j < 4; ++j) {
        float4 v; v.x = lrelu(acc[0][j]+bb0); v.y = lrelu(acc[1][j]+bb1);
        v.z = lrelu(acc[2][j]+bb2); v.w = lrelu(acc[3][j]+bb3);
        *(float4*)&H1[(j0+j)*256 + p0] = v;
      }
    }
    __syncthreads();
    {
      const int p0 = (t & 63) * 4, j0 = (t >> 6) * 4;
      float acc[4][4];
#pragma unroll
      for (int r = 0; r < 4; ++r)
#pragma unroll
        for (int j = 0; j < 4; ++j) acc[r][j] = 0.f;
      for (int c = 0; c < 256; c += 4) {
        float4 wv[4];
#pragma unroll
        for (int cc = 0; cc < 4; ++cc) wv[cc] = *(const float4*)&W2t[(size_t)(c+cc)*256 + p0];
#pragma unroll
        for (int j = 0; j < 4; ++j) {
          const float4 x = *(const float4*)&H1[(j0+j)*256 + c];
          acc[0][j] += wv[0].x*x.x + wv[1].x*x.y + wv[2].x*x.z + wv[3].x*x.w;
          acc[1][j] += wv[0].y*x.x + wv[1].y*x.y + wv[2].y*x.z + wv[3].y*x.w;
          acc[2][j] += wv[0].z*x.x + wv[1].z*x.y + wv[2].z*x.z + wv[3].z*x.w;
          acc[3][j] += wv[0].w*x.x + wv[1].w*x.y + wv[2].w*x.z + wv[3].w*x.w;
        }
      }
      const float bb0 = b2[p0], bb1 = b2[p0+1], bb2 = b2[p0+2], bb3 = b2[p0+3];
#pragma unroll
      for (int j = 0; j < 4; ++j) {
        float4 v; v.x = lrelu(acc[0][j]+bb0); v.y = lrelu(acc[1][j]+bb1);
        v.z = lrelu(acc[2][j]+bb2); v.w = lrelu(acc[3][j]+bb3);
        *(float4*)&H2[(j0+j)*256 + p0] = v;
      }
    }
    __syncthreads();
    {
      const int p0 = (t & 63) * 2, j0 = (t >> 6) * 4;
      float acc[2][4];
#pragma unroll
      for (int r = 0; r < 2; ++r)
#pragma unroll
        for (int j = 0; j < 4; ++j) acc[r][j] = 0.f;
      for (int c = 0; c < 128; c += 4) {
        float2 wv[4];
#pragma unroll
        for (int cc = 0; cc < 4; ++cc) wv[cc] = *(const float2*)&Wdt[(size_t)(c+cc)*128 + p0];
#pragma unroll
        for (int j = 0; j < 4; ++j) {
          const float4 x = *(const float4*)&PA[(j0+j)*128 + c];
          acc[0][j] += wv[0].x*x.x + wv[1].x*x.y + wv[2].x*x.z + wv[3].x*x.w;
          acc[1][j] += wv[0].y*x.x + wv[1].y*x.y + wv[2].y*x.z + wv[3].y*x.w;
        }
      }
      for (int c = 0; c < 256; c += 4) {
        float2 wv[4];
#pragma unroll
        for (int cc = 0; cc < 4; ++cc) wv[cc] = *(const float2*)&W3t[(size_t)(c+cc)*128 + p0];
#pragma unroll
        for (int j = 0; j < 4; ++j) {
          const float4 x = *(const float4*)&H2[(j0+j)*256 + c];
          acc[0][j] += wv[0].x*x.x + wv[1].x*x.y + wv[2].x*x.z + wv[3].x*x.w;
          acc[1][j] += wv[0].y*x.x + wv[1].y*x.y + wv[2].y*x.z + wv[3].y*x.w;
        }
      }
      const float bb0 = b3[p0], bb1 = b3[p0+1];
#pragma unroll
      for (int j = 0; j < 4; ++j) {
        const float o0 = acc[0][j] + bb0 + PA[(j0+j)*128 + p0];
        const float o1 = acc[1][j] + bb1 + PA[(j0+j)*128 + p0 + 1];
        psiA[(size_t)(cbase + j0 + j)*128 + p0]     = f2bf(o0);
        psiA[(size_t)(cbase + j0 + j)*128 + p0 + 1] = f2bf(o1);
      }
    }
  } else {
    // ---------------- mlp_v: 8 combos, 192 active thr ----------------
    const bool act = (t < 192);
    const int cbase = (b - b/3 - 1) * 8;
    float* PV  = sm;            // [8][288]
    float* HV  = sm + 2304;     // [8][576]
    float* HV2 = sm + 6912;     // [8][576]

    for (int q = t; q < 2304; q += 256) {   // all 256 threads stage
      const int j = q / 288, r = q % 288, i = r / 96, o = r % 96;
      PV[j*288 + i*96 + o] = bf2f(psiV[(size_t)(cbase + j)*288 + o*3 + i]);
    }
    __syncthreads();
    if (act) {
      const int p0 = (t % 96) * 2, j0 = (t / 96) * 4;
      float acc[2][4][3];
#pragma unroll
      for (int r = 0; r < 2; ++r)
#pragma unroll
        for (int j = 0; j < 4; ++j) { acc[r][j][0]=0.f; acc[r][j][1]=0.f; acc[r][j][2]=0.f; }
      for (int c = 0; c < 96; c += 4) {
        float2 wv[4];
#pragma unroll
        for (int cc = 0; cc < 4; ++cc) wv[cc] = *(const float2*)&V1t[(size_t)(c+cc)*192 + p0];
#pragma unroll
        for (int j = 0; j < 4; ++j)
#pragma unroll
          for (int i = 0; i < 3; ++i) {
            const float4 x = *(const float4*)&PV[(j0+j)*288 + i*96 + c];
            acc[0][j][i] += wv[0].x*x.x + wv[1].x*x.y + wv[2].x*x.z + wv[3].x*x.w;
            acc[1][j][i] += wv[0].y*x.x + wv[1].y*x.y + wv[2].y*x.z + wv[3].y*x.w;
          }
      }
      float scl[2][4];
#pragma unroll
      for (int r = 0; r < 2; ++r)
#pragma unroll
        for (int j = 0; j < 4; ++j) {
          const float nn = sqrtf(acc[r][j][0]*acc[r][j][0] + acc[r][j][1]*acc[r][j][1]
                               + acc[r][j][2]*acc[r][j][2] + 1e-12f);
          scl[r][j] = (2.f / (1.f + expf(-nn)) - 1.f) / nn;
        }
#pragma unroll
      for (int j = 0; j < 4; ++j)
#pragma unroll
        for (int i = 0; i < 3; ++i) {
          float2 v;
          v.x = acc[0][j][i]*scl[0][j]; v.y = acc[1][j][i]*scl[1][j];
          *(float2*)&HV[(j0+j)*576 + i*192 + p0] = v;
        }
    }
    __syncthreads();
    if (act) {
      const int p0 = (t % 96) * 2, j0 = (t / 96) * 4;
      float acc[2][4][3];
#pragma unroll
      for (int r = 0; r < 2; ++r)
#pragma unroll
        for (int j = 0; j < 4; ++j) { acc[r][j][0]=0.f; acc[r][j][1]=0.f; acc[r][j][2]=0.f; }
      for (int c = 0; c < 192; c += 4) {
        float2 wv[4];
#pragma unroll
        for (int cc = 0; cc < 4; ++cc) wv[cc] = *(const float2*)&V2t[(size_t)(c+cc)*192 + p0];
#pragma unroll
        for (int j = 0; j < 4; ++j)
#pragma unroll
          for (int i = 0; i < 3; ++i) {
            const float4 x = *(const float4*)&HV[(j0+j)*576 + i*192 + c];
            acc[0][j][i] += wv[0].x*x.x + wv[1].x*x.y + wv[2].x*x.z + wv[3].x*x.w;
            acc[1][j][i] += wv[0].y*x.x + wv[1].y*x.y + wv[2].y*x.z + wv[3].y*x.w;
          }
      }
      float scl[2][4];
#pragma unroll
      for (int r = 0; r < 2; ++r)
#pragma unroll
        for (int j = 0; j < 4; ++j) {
          const float nn = sqrtf(acc[r][j][0]*acc[r][j][0] + acc[r][j][1]*acc[r][j][1]
                               + acc[r][j][2]*acc[r][j][2] + 1e-12f);
          scl[r][j] = (2.f / (1.f + expf(-nn)) - 1.f) / nn;
        }
#pragma unroll
      for (int j = 0; j < 4; ++j)
#pragma unroll
        for (int i = 0; i < 3; ++i) {
          float2 v;
          v.x = acc[0][j][i]*scl[0][j]; v.y = acc[1][j][i]*scl[1][j];
          *(float2*)&HV2[(j0+j)*576 + i*192 + p0] = v;
        }
    }
    __syncthreads();
    if (act) {
      const int p0 = t % 96, j0 = (t / 96) * 4;
      float acc[4][3];
#pragma unroll
      for (int j = 0; j < 4; ++j) { acc[j][0]=0.f; acc[j][1]=0.f; acc[j][2]=0.f; }
      for (int c = 0; c < 96; c += 4) {
        float wv[4];
#pragma unroll
        for (int cc = 0; cc < 4; ++cc) wv[cc] = Vdt[(size_t)(c+cc)*96 + p0];
#pragma unroll
        for (int j = 0; j < 4; ++j)
#pragma unroll
          for (int i = 0; i < 3; ++i) {
            const float4 x = *(const float4*)&PV[(j0+j)*288 + i*96 + c];
            acc[j][i] += wv[0]*x.x + wv[1]*x.y + wv[2]*x.z + wv[3]*x.w;
          }
      }
      for (int c = 0; c < 192; c += 4) {
        float wv[4];
#pragma unroll
        for (int cc = 0; cc < 4; ++cc) wv[cc] = V3t[(size_t)(c+cc)*96 + p0];
#pragma unroll
        for (int j = 0; j < 4; ++j)
#pragma unroll
          for (int i = 0; i < 3; ++i) {
            const float4 x = *(const float4*)&HV2[(j0+j)*576 + i*192 + c];
            acc[j][i] += wv[0]*x.x + wv[1]*x.y + wv[2]*x.z + wv[3]*x.w;
          }
      }
#pragma unroll
      for (int j = 0; j < 4; ++j)
#pragma unroll
        for (int i = 0; i < 3; ++i) {
          const float v = acc[j][i] + PV[(j0+j)*288 + i*96 + p0];
          psiV[(size_t)(cbase + j0 + j)*288 + p0*3 + i] = f2bf(v);
        }
    }
  }
}

// ---------------------------------------------------------------------------
// Gather (by src) + fused output projection. Block per src atom, 256 thr.
// ---------------------------------------------------------------------------
__global__ __launch_bounds__(256, 2) void gather_out_kernel(
    const int* __restrict__ soff, const int* __restrict__ sperm,
    const unsigned short* __restrict__ psiA, const unsigned short* __restrict__ psiV,
    const unsigned short* __restrict__ psiD,
    const float* __restrict__ Wa, const float* __restrict__ Wv, const float* __restrict__ Wd,
    float* __restrict__ out)
{
  __shared__ float bs[1984];
  const int n = blockIdx.x, t = threadIdx.x;
  const int s0 = soff[n], s1 = soff[n + 1];
  float acc[8];
#pragma unroll
  for (int u = 0; u < 8; ++u) acc[u] = 0.f;
  for (int p2 = s0; p2 < s1; ++p2) {
    const int slot = sperm[p2];
    const unsigned short* ra = psiA + (size_t)slot * 256;
    const unsigned short* rv = psiV + (size_t)slot * 576;
    const unsigned short* rd = psiD + (size_t)slot * 1152;
#pragma unroll
    for (int u = 0; u < 8; ++u) {
      const int v = t + 256 * u;
      if (v < 256)        acc[u] += bf2f(ra[v]);
      else if (v < 832)   acc[u] += bf2f(rv[v - 256]);
      else if (v < 1984)  acc[u] += bf2f(rd[v - 832]);
    }
  }
#pragma unroll
  for (int u = 0; u < 8; ++u) {
    const int v = t + 256 * u;
    if (v < 1984) bs[v] = acc[u];
  }
  __syncthreads();
  if (t < 128) {
    const float* W = &Wa[(size_t)t * 256];
    float a = 0.f;
    for (int c = 0; c < 256; c += 4) a += dot4f(*(const float4*)&W[c], *(const float4*)&bs[c]);
    out[(size_t)n*128 + t] = a;
  }
  if (t < 96) {
    const float* W = &Wv[(size_t)t * 192];
    float a0 = 0.f, a1 = 0.f, a2 = 0.f;
    for (int c = 0; c < 192; ++c) {
      const float w = W[c]; const float* x = &bs[256 + c*3];
      a0 = fmaf(w, x[0], a0); a1 = fmaf(w, x[1], a1); a2 = fmaf(w, x[2], a2);
    }
    float* d = &out[OUT_V + ((size_t)n*96 + t)*3];
    d[0] = a0; d[1] = a1; d[2] = a2;
  }
  if (t < 64) {
    const float* W = &Wd[(size_t)t * 128];
    float a[9] = {0,0,0,0,0,0,0,0,0};
    for (int c = 0; c < 128; ++c) {
      const float w = W[c]; const float* x = &bs[832 + c*9];
#pragma unroll
      for (int j = 0; j < 9; ++j) a[j] = fmaf(w, x[j], a[j]);
    }
    float* d = &out[OUT_D + ((size_t)n*64 + t)*9];
#pragma unroll
    for (int j = 0; j < 9; ++j) d[j] = a[j];
  }
}

// ---------------------------------------------------------------------------
// Host entry
// ---------------------------------------------------------------------------
extern "C" void kernel_launch(void* const* d_in, const int* in_sizes, int n_in,
                              void* d_out, int out_size, void* d_ws, size_t ws_size,
                              hipStream_t stream) {
  (void)in_sizes; (void)n_in; (void)out_size; (void)ws_size;
  const int*   src  = (const int*)d_in[0];
  const int*   dst  = (const int*)d_in[1];
  const float* r_ij = (const float*)d_in[2];
  const float* x_a  = (const float*)d_in[3];
  const float* x_v  = (const float*)d_in[4];
  const float* x_d  = (const float*)d_in[5];
  const float* P[13];
  for (int i = 0; i < 13; ++i) P[i] = (const float*)d_in[6 + i];
  const float* W_in_a  = (const float*)d_in[19];
  const float* W_in_v  = (const float*)d_in[20];
  const float* W_in_d  = (const float*)d_in[21];
  const float* W_out_a = (const float*)d_in[22];
  const float* W_out_v = (const float*)d_in[23];
  const float* W_out_d = (const float*)d_in[24];
  const float* Wd_a = (const float*)d_in[25];
  const float* W1   = (const float*)d_in[26];
  const float* b1   = (const float*)d_in[27];
  const float* W2   = (const float*)d_in[28];
  const float* b2   = (const float*)d_in[29];
  const float* W3   = (const float*)d_in[30];
  const float* b3   = (const float*)d_in[31];
  const float* Vd   = (const float*)d_in[32];
  const float* V1   = (const float*)d_in[33];
  const float* V2   = (const float*)d_in[34];
  const float* V3   = (const float*)d_in[35];

  float* ws = (float*)d_ws;
  float* Pt = ws;
  int*   ib = (int*)(ws + INT_OFF);
  unsigned short* psiA = (unsigned short*)(ws + PSIA_OFF);
  unsigned short* psiV = (unsigned short*)(ws + PSIV_OFF);
  unsigned short* psiD = (unsigned short*)(ws + PSID_OFF);
  float* ot = (float*)d_out;   // head of d_out = transposed-weight scratch

  // 1) fused transposes (2 launches instead of 21)
  P13 ps; for (int i = 0; i < 13; ++i) ps.p[i] = P[i];
  transP_all_kernel<<<(111616 + 255) / 256, 256, 0, stream>>>(ps, Pt);
  P8 pw;
  pw.p[0] = W1; pw.p[1] = W2; pw.p[2] = W3; pw.p[3] = Wd_a;
  pw.p[4] = V1; pw.p[5] = V2; pw.p[6] = V3; pw.p[7] = Vd;
  transW_all_kernel<<<(230400 + 255) / 256, 256, 0, stream>>>(pw, ot);

  // 2) zero sort counters
  hipMemsetAsync(ib, 0, 20000 * sizeof(int), stream);

  // 3) sorts + per-edge encodings (4 launches)
  const int egrid = (NE + 255) / 256;
  hist2_kernel<<<egrid, 256, 0, stream>>>(dst, src, ib + ICNT, ib + SCNT);
  scan2_kernel<<<2, 256, 0, stream>>>(ib + ICNT, ib + IOFF, ib + SCNT, ib + SOFF);
  sort_scatter_kernel<<<egrid, 256, 0, stream>>>(dst, ib + IOFF, ib + ICUR, ib + IEIDX, ib + ISLOT);
  ssort_phi_kernel<<<2 * egrid, 256, 0, stream>>>(src, ib + ISLOT, ib + SOFF, ib + SCUR,
                                                  ib + SPERM, ib + IEIDX, r_ij, ws + PHI_OFF);

  // 4) input projections
  proj_in_kernel<<<NA, 256, 0, stream>>>(x_a, x_v, x_d, W_in_a, W_in_v, W_in_d,
                                         ws + A_OFF, ws + V_OFF, ws + D_OFF);

  // 5) FUSED message passes: a/v/d blocks co-resident (type = blockIdx%3)
  pass_fused_kernel<<<3 * NA, 256, 0, stream>>>(ib + IOFF, ws + PHI_OFF, Pt,
                                                ws + A_OFF, ws + V_OFF, ws + D_OFF,
                                                psiA, psiV, psiD);

  // 6) FUSED edge MLPs (a: 5000 blocks, v: 10000 blocks)
  mlp_fused_kernel<<<15000, 256, 0, stream>>>(psiA, psiV,
                                              ot + WTD, ot + WT1, b1, ot + WT2, b2, ot + WT3, b3,
                                              ot + VTD, ot + VT1, ot + VT2, ot + VT3);

  // 7) gather by src + fused output projection (overwrites all of d_out)
  gather_out_kernel<<<NA, 256, 0, stream>>>(ib + SOFF, ib + SPERM,
                                            psiA, psiV, psiD,
                                            W_out_a, W_out_v, W_out_d, (float*)d_out);
}

// Round 9
// 3739.089 us; speedup vs baseline: 1.6906x; 1.6906x over previous
//
#include <hip/hip_runtime.h>
#include <hip/hip_bf16.h>

// ---------------------------------------------------------------------------
// Problem constants
// ---------------------------------------------------------------------------
#define NA 5000           // atoms
#define NE 40000          // edges
// DA=128, DV=96, DD=64, NL=8, L=2

// ---------------------------------------------------------------------------
// Workspace layout (float indices)
// ---------------------------------------------------------------------------
static const int POFF[13] = {0, 131072, 229376, 294912, 368640, 466944, 516096,
                             589824, 663552, 696320, 761856, 811008, 843776};
#define A_OFF    892928          // a  [2][NA][128] fp32
#define V_OFF    2172928         // v  [2][NA][288] fp32
#define D_OFF    5052928         // d  [2][NA][576] fp32
#define PHI_OFF  10812928        // [NE][12] fp32
#define PSIA_OFF 11292928        // bf16 [NE][256]
#define PSIV_OFF 16412928        // bf16 [NE][576]
#define PSID_OFF 27932928        // bf16 [NE][1152]
#define INT_OFF  50972928
// int region (indices into (int*)(ws + INT_OFF))
#define ICNT  0        // [5000]
#define ICUR  5000     // [5000]
#define SCNT  10000    // [5000]
#define SCUR  15000    // [5000]
#define IOFF  20000    // [5001]
#define SOFF  25008    // [5001]
#define IEIDX 30016    // [NE]
#define ISLOT 70016    // [NE]
#define SPERM 110016   // [NE]

// output layout (floats)
#define OUT_V 640000
#define OUT_D 2080000

// transposed-MLP-weight scratch at the HEAD of d_out (free until gather).
#define WT1 0          // [128][256]
#define WT2 32768      // [256][256]
#define WT3 98304      // [256][128]
#define WTD 131072     // [128][128]
#define VT1 147456     // [96][192]
#define VT2 165888     // [192][192]
#define VT3 202752     // [192][96]
#define VTD 221184     // [96][96]   -> ends 230400

#define OFF_000 POFF[0]
#define OFF_110 POFF[1]
#define OFF_220 POFF[2]
#define OFF_011 POFF[3]
#define OFF_101 POFF[4]
#define OFF_121 POFF[5]
#define OFF_211 POFF[6]
#define OFF_111 POFF[7]
#define OFF_022 POFF[8]
#define OFF_202 POFF[9]
#define OFF_112 POFF[10]
#define OFF_222 POFF[11]
#define OFF_212 POFF[12]

__device__ __forceinline__ float dot4f(float4 a, float4 b) {
  return a.x*b.x + a.y*b.y + a.z*b.z + a.w*b.w;
}
__device__ __forceinline__ float lrelu(float x) { return x > 0.f ? x : 0.1f*x; }
__device__ __forceinline__ float bf2f(unsigned short u) {
  union { unsigned int i; float f; } x; x.i = ((unsigned int)u) << 16; return x.f;
}
__device__ __forceinline__ unsigned short f2bf(float f) {
  union { unsigned int i; float f; } x; x.f = f;
  unsigned int r = x.i + 0x7FFFu + ((x.i >> 16) & 1u);
  return (unsigned short)(r >> 16);
}

struct P13 { const float* p[13]; };
struct P8  { const float* p[8]; };

// ---------------------------------------------------------------------------
// Fused P transpose: all 13 tensors [O][8][C] -> [C][O][8] in one launch.
// ---------------------------------------------------------------------------
__global__ __launch_bounds__(256) void transP_all_kernel(P13 ps, float* __restrict__ Pt)
{
  static const int Od[13] = {128,128,128, 96, 96, 96, 96, 96, 64, 64, 64, 64, 64};
  static const int Cd[13] = {128, 96, 64, 96,128, 64, 96, 96, 64,128, 96, 64, 96};
  static const int POF[13] = {0, 131072, 229376, 294912, 368640, 466944, 516096,
                              589824, 663552, 696320, 761856, 811008, 843776};
  static const int CUM[14] = {0,16384,28672,36864,46080,58368,64512,73728,
                              82944,87040,95232,101376,105472,111616};
  int idx = blockIdx.x * 256 + threadIdx.x;
  if (idx >= 111616) return;
  int i = 0;
  while (idx >= CUM[i+1]) ++i;
  const int r = idx - CUM[i];
  const int O = Od[i], C = Cd[i];
  const int o = r / C, c = r % C;
  const float* src = ps.p[i];
  float* dst = Pt + POF[i];
#pragma unroll
  for (int k = 0; k < 8; ++k)
    dst[((size_t)c * O + o) * 8 + k] = src[((size_t)o * 8 + k) * C + c];
}

// ---------------------------------------------------------------------------
// Fused MLP-weight transpose: 8 matrices [R][C] -> [C][R], packed at CUM[i].
// ---------------------------------------------------------------------------
__global__ __launch_bounds__(256) void transW_all_kernel(P8 ps, float* __restrict__ ot)
{
  static const int R[8]   = {256,256,128,128,192,192, 96, 96};
  static const int C[8]   = {128,256,256,128, 96,192,192, 96};
  static const int CUM[9] = {0,32768,98304,131072,147456,165888,202752,221184,230400};
  int idx = blockIdx.x * 256 + threadIdx.x;
  if (idx >= 230400) return;
  int i = 0;
  while (idx >= CUM[i+1]) ++i;
  const int r = idx - CUM[i];
  const int rr = r / C[i], cc = r % C[i];
  ot[(size_t)CUM[i] + (size_t)cc * R[i] + rr] = ps.p[i][r];
}

// ---------------------------------------------------------------------------
// Counting sorts (merged where dependency-free)
// ---------------------------------------------------------------------------
__global__ __launch_bounds__(256) void hist2_kernel(
    const int* __restrict__ dstk, const int* __restrict__ srck,
    int* __restrict__ cntd, int* __restrict__ cnts)
{
  int e = blockIdx.x * 256 + threadIdx.x;
  if (e < NE) { atomicAdd(&cntd[dstk[e]], 1); atomicAdd(&cnts[srck[e]], 1); }
}

__global__ __launch_bounds__(256) void scan2_kernel(
    const int* __restrict__ cnt0, int* __restrict__ off0,
    const int* __restrict__ cnt1, int* __restrict__ off1)
{
  const int* cnt = (blockIdx.x == 0) ? cnt0 : cnt1;
  int* off       = (blockIdx.x == 0) ? off0 : off1;
  __shared__ int part[256];
  const int t = threadIdx.x;
  int loc[20]; int s = 0;
#pragma unroll
  for (int i = 0; i < 20; ++i) {
    int idx = t * 20 + i;
    int v = (idx < NA) ? cnt[idx] : 0;
    loc[i] = v; s += v;
  }
  part[t] = s; __syncthreads();
  for (int ofs = 1; ofs < 256; ofs <<= 1) {
    int v = (t >= ofs) ? part[t - ofs] : 0;
    __syncthreads();
    part[t] += v;
    __syncthreads();
  }
  int run = part[t] - s;   // exclusive prefix
#pragma unroll
  for (int i = 0; i < 20; ++i) {
    int idx = t * 20 + i;
    if (idx < NA) off[idx] = run;
    run += loc[i];
  }
  if (t == 255) off[NA] = run;
}

__global__ __launch_bounds__(256) void sort_scatter_kernel(
    const int* __restrict__ dst, const int* __restrict__ off,
    int* __restrict__ cur, int* __restrict__ eidx, int* __restrict__ islot)
{
  int e = blockIdx.x * 256 + threadIdx.x;
  if (e >= NE) return;
  int d = dst[e];
  int pos = off[d] + atomicAdd(&cur[d], 1);
  eidx[pos] = e;
  islot[e] = pos;
}

// ssort + phi fused (both depend only on sort_scatter outputs)
__global__ __launch_bounds__(256) void ssort_phi_kernel(
    const int* __restrict__ src, const int* __restrict__ islot,
    const int* __restrict__ soff, int* __restrict__ scur, int* __restrict__ sperm,
    const int* __restrict__ eidx, const float* __restrict__ r_ij, float* __restrict__ phi)
{
  const int B = (NE + 255) / 256;
  if ((int)blockIdx.x < B) {
    int e = blockIdx.x * 256 + threadIdx.x;
    if (e >= NE) return;
    int s = src[e];
    int pos = soff[s] + atomicAdd(&scur[s], 1);
    sperm[pos] = islot[e];
  } else {
    int p = (blockIdx.x - B) * 256 + threadIdx.x;
    if (p >= NE) return;
    int e = eidx[p];
    const float rx = r_ij[e*3+0], ry = r_ij[e*3+1], rz = r_ij[e*3+2];
    const float r2 = rx*rx + ry*ry + rz*rz;
    const float r = sqrtf(r2 + 1e-12f);
#pragma unroll
    for (int k = 0; k < 8; ++k) {
      const float z = 7.f*r - (float)k;
      phi[(size_t)p*12 + k] = expf(-0.5f*z*z);
    }
    const float nn = sqrtf(49.f*r2 + 1e-12f);
    const float sc = (2.f / (1.f + expf(-nn)) - 1.f) / nn;
    phi[(size_t)p*12 + 8]  = 7.f*rx*sc;
    phi[(size_t)p*12 + 9]  = 7.f*ry*sc;
    phi[(size_t)p*12 + 10] = 7.f*rz*sc;
    phi[(size_t)p*12 + 11] = 0.f;
  }
}

// ---------------------------------------------------------------------------
// Input projection (per atom)
// ---------------------------------------------------------------------------
__global__ __launch_bounds__(256) void proj_in_kernel(
    const float* __restrict__ x_a, const float* __restrict__ x_v, const float* __restrict__ x_d,
    const float* __restrict__ Wa, const float* __restrict__ Wv, const float* __restrict__ Wd,
    float* __restrict__ a_ws, float* __restrict__ v_ws, float* __restrict__ d_ws)
{
  __shared__ float xs[992];
  const int n = blockIdx.x, t = threadIdx.x;
  for (int q = t; q < 128; q += 256) xs[q]       = x_a[(size_t)n*128 + q];
  for (int q = t; q < 288; q += 256) xs[128 + q] = x_v[(size_t)n*288 + q];
  for (int q = t; q < 576; q += 256) xs[416 + q] = x_d[(size_t)n*576 + q];
  __syncthreads();
  {
    const float* W = &Wa[(size_t)t * 128];
    float acc = 0.f;
    for (int c = 0; c < 128; c += 4) acc += dot4f(*(const float4*)&W[c], *(const float4*)&xs[c]);
    int l = t >> 7, o = t & 127;
    a_ws[((size_t)l*NA + n)*128 + o] = acc;
  }
  if (t < 192) {
    const float* W = &Wv[(size_t)t * 96];
    float a0 = 0.f, a1 = 0.f, a2 = 0.f;
    for (int c = 0; c < 96; ++c) {
      float w = W[c]; const float* x = &xs[128 + c*3];
      a0 = fmaf(w, x[0], a0); a1 = fmaf(w, x[1], a1); a2 = fmaf(w, x[2], a2);
    }
    int l = t / 96, o = t % 96;
    float* dstp = &v_ws[(((size_t)l*NA + n)*96 + o)*3];
    dstp[0] = a0; dstp[1] = a1; dstp[2] = a2;
  }
  if (t < 128) {
    const float* W = &Wd[(size_t)t * 64];
    float acc[9] = {0,0,0,0,0,0,0,0,0};
    for (int c = 0; c < 64; ++c) {
      float w = W[c]; const float* x = &xs[416 + c*9];
#pragma unroll
      for (int j = 0; j < 9; ++j) acc[j] = fmaf(w, x[j], acc[j]);
    }
    int l = t >> 6, o = t & 63;
    float* dstp = &d_ws[(((size_t)l*NA + n)*64 + o)*9];
#pragma unroll
    for (int j = 0; j < 9; ++j) dstp[j] = acc[j];
  }
}

// ---------------------------------------------------------------------------
// Z helpers.  Pt layout [C][O][8].
// ---------------------------------------------------------------------------
template<int O, int C, int NMU>
__device__ __forceinline__ void zcompute(const float* __restrict__ Pt,
    const float* __restrict__ xl, int o, float z[8][NMU])
{
#pragma unroll
  for (int k = 0; k < 8; ++k)
#pragma unroll
    for (int m = 0; m < NMU; ++m) z[k][m] = 0.f;
  const float* p = Pt + o * 8;
#pragma unroll 2
  for (int c = 0; c < C; ++c, p += O*8) {
    const float4 pa = *(const float4*)p;
    const float4 pb = *(const float4*)(p + 4);
#pragma unroll
    for (int m = 0; m < NMU; ++m) {
      const float xv = xl[c * NMU + m];
      z[0][m] = fmaf(pa.x, xv, z[0][m]);
      z[1][m] = fmaf(pa.y, xv, z[1][m]);
      z[2][m] = fmaf(pa.z, xv, z[2][m]);
      z[3][m] = fmaf(pa.w, xv, z[3][m]);
      z[4][m] = fmaf(pb.x, xv, z[4][m]);
      z[5][m] = fmaf(pb.y, xv, z[5][m]);
      z[6][m] = fmaf(pb.z, xv, z[6][m]);
      z[7][m] = fmaf(pb.w, xv, z[7][m]);
    }
  }
}

// half-k variant, generic NMU: z[4][NMU] for k range [kh*4, kh*4+4)
template<int O, int C, int NMU>
__device__ __forceinline__ void zcompute_k4n(const float* __restrict__ Pt,
    const float* __restrict__ xl, int o, int kh, float z[4][NMU])
{
#pragma unroll
  for (int k = 0; k < 4; ++k)
#pragma unroll
    for (int m = 0; m < NMU; ++m) z[k][m] = 0.f;
  const float* p = Pt + o * 8 + kh * 4;
#pragma unroll 2
  for (int c = 0; c < C; ++c, p += O*8) {
    const float4 pa = *(const float4*)p;
#pragma unroll
    for (int m = 0; m < NMU; ++m) {
      const float xv = xl[c*NMU + m];
      z[0][m] = fmaf(pa.x, xv, z[0][m]);
      z[1][m] = fmaf(pa.y, xv, z[1][m]);
      z[2][m] = fmaf(pa.z, xv, z[2][m]);
      z[3][m] = fmaf(pa.w, xv, z[3][m]);
    }
  }
}

template<int NMU>
__device__ __forceinline__ float kdot(const float z[8][NMU], int m, const float* rr) {
  float s = z[0][m] * rr[0];
#pragma unroll
  for (int k = 1; k < 8; ++k) s = fmaf(z[k][m], rr[k], s);
  return s;
}
template<int NMU>
__device__ __forceinline__ float kdot4n(const float z[4][NMU], int m, const float* rr) {
  float s = z[0][m] * rr[0];
#pragma unroll
  for (int k = 1; k < 4; ++k) s = fmaf(z[k][m], rr[k], s);
  return s;
}

// shared feature layout (floats), SINGLE atom, both l:
//   XA [l][128]=256 | XV [l][288]=576 | XD [l][576]=1152  -> 1984
#define F1_XA 0
#define F1_XV 256
#define F1_XD 832
#define F1_TOT 1984

template<int NT>
__device__ __forceinline__ void load_features1(float* sm, int t, int n,
    const float* __restrict__ a_ws, const float* __restrict__ v_ws, const float* __restrict__ d_ws)
{
  for (int q = t; q < 256; q += NT)
    sm[F1_XA + q] = a_ws[((size_t)(q>>7)*NA + n)*128 + (q & 127)];
  for (int q = t; q < 576; q += NT)
    sm[F1_XV + q] = v_ws[((size_t)(q/288)*NA + n)*288 + (q % 288)];
  for (int q = t; q < 1152; q += NT)
    sm[F1_XD + q] = d_ws[((size_t)(q/576)*NA + n)*576 + (q % 576)];
}

// ---------------------------------------------------------------------------
// FUSED message pass: grid 3*NA, 256 thr.  type = blockIdx%3.
// A: 256 thr (o x l), window 16.
// V: 192 active thr (o x l), window 10.
// D: 128 active thr (o x l), window 5, plain += (round-8 LDS atomics REVERTED:
//    LDS atomicAdd RMW serialization cost >> the z-FLOP saving).
// LDS max 7864 floats = 31456 B -> 5 blocks/CU (was 4), occ cap 62.5%.
// ---------------------------------------------------------------------------
__global__ __launch_bounds__(256, 5) void pass_fused_kernel(
    const int* __restrict__ off, const float* __restrict__ phi,
    const float* __restrict__ Pt,
    const float* __restrict__ a_ws, const float* __restrict__ v_ws, const float* __restrict__ d_ws,
    unsigned short* __restrict__ psiA, unsigned short* __restrict__ psiV,
    unsigned short* __restrict__ psiD)
{
  __shared__ float sm[7864];   // max(a:6272, v:7864, d:7804) floats = 31456 B
  const int b = blockIdx.x;
  const int type = b % 3;
  const int n = b / 3;
  const int t = threadIdx.x;
  const int off0 = off[n], off1 = off[n + 1];
  const int d = off1 - off0;
  if (d == 0) return;   // uniform across block: no thread has hit a barrier

  load_features1<256>(sm, t, n, a_ws, v_ws, d_ws);   // all 256 threads help

  if (type == 0) {
    // ---------------- pass A: 256 thr, window 16 ----------------
    const int o = t & 127, l = t >> 7;
    const float* xa = &sm[F1_XA + l*128];
    const float* xv = &sm[F1_XV + l*288];
    const float* xd = &sm[F1_XD + l*576];
    float* sphi = &sm[F1_TOT];            // 192
    float* psis = &sm[F1_TOT + 192];      // [16][256]

    const int nw = (d + 15) >> 4;
    for (int w = 0; w < nw; ++w) {
      const int b0 = w * 16;
      __syncthreads();
      if (t < 192) {
        const int s = t / 12, f = t % 12;
        sphi[t] = (b0 + s < d) ? phi[(size_t)(off0 + b0 + s)*12 + f] : 0.f;
      }
      __syncthreads();

      {
        float z[8][1];
        zcompute<128,128,1>(Pt + OFF_000, xa, o, z);
#pragma unroll
        for (int e = 0; e < 16; ++e)
          psis[e*256 + t] = kdot<1>(z, 0, &sphi[e*12]);
      }
      {
        float z[8][3];
        zcompute<128,96,3>(Pt + OFF_110, xv, o, z);
#pragma unroll
        for (int e = 0; e < 16; ++e) {
          const float* ph = &sphi[e*12];
          psis[e*256 + t] += ph[8]*kdot<3>(z,0,ph) + ph[9]*kdot<3>(z,1,ph) + ph[10]*kdot<3>(z,2,ph);
        }
      }
#pragma unroll
      for (int kh = 0; kh < 2; ++kh) {
        float z[4][9];
        zcompute_k4n<128,64,9>(Pt + OFF_220, xd, o, kh, z);
#pragma unroll
        for (int e = 0; e < 16; ++e) {
          const float* ph = &sphi[e*12];
          const float* rr = ph + kh*4;
          float s[9];
#pragma unroll
          for (int m = 0; m < 9; ++m) s[m] = kdot4n<9>(z, m, rr);
          const float q0 = ph[8], q1 = ph[9], q2 = ph[10];
          psis[e*256 + t] += q0*(q0*s[0] + q1*s[1] + q2*s[2])
                           + q1*(q0*s[3] + q1*s[4] + q2*s[5])
                           + q2*(q0*s[6] + q1*s[7] + q2*s[8]);
        }
      }
#pragma unroll
      for (int e = 0; e < 16; ++e)
        if (b0 + e < d) psiA[(size_t)(off0 + b0 + e)*256 + t] = f2bf(psis[e*256 + t]);
    }
  } else if (type == 1) {
    // ---------------- pass V: 192 active thr, window 10 ----------------
    const bool act = (t < 192);
    const int o = t % 96, l = (t / 96) & 1;   // clamped for surplus lanes
    const float* xa = &sm[F1_XA + l*128];
    const float* xv = &sm[F1_XV + l*288];
    const float* xd = &sm[F1_XD + l*576];
    float* sphi = &sm[F1_TOT];            // 120
    float* psis = &sm[F1_TOT + 120];      // [10][3][192]

    const int nw = (d + 9) / 10;
    for (int w = 0; w < nw; ++w) {
      const int b0 = w * 10;
      __syncthreads();
      if (t < 120) {
        const int s = t / 12, f = t % 12;
        sphi[t] = (b0 + s < d) ? phi[(size_t)(off0 + b0 + s)*12 + f] : 0.f;
      }
      __syncthreads();

      if (act) {
        {
          float z[8][3];
          zcompute<96,96,3>(Pt + OFF_011, xv, o, z);
#pragma unroll
          for (int e = 0; e < 10; ++e) {
            const float* ph = &sphi[e*12];
            float* pb = &psis[e*576 + t];
            pb[0]   = kdot<3>(z,0,ph);
            pb[192] = kdot<3>(z,1,ph);
            pb[384] = kdot<3>(z,2,ph);
          }
        }
        {
          float z[8][1];
          zcompute<96,128,1>(Pt + OFF_101, xa, o, z);
#pragma unroll
          for (int e = 0; e < 10; ++e) {
            const float* ph = &sphi[e*12];
            const float s0 = kdot<1>(z,0,ph);
            float* pb = &psis[e*576 + t];
            pb[0] += ph[8]*s0; pb[192] += ph[9]*s0; pb[384] += ph[10]*s0;
          }
        }
#pragma unroll
        for (int kh = 0; kh < 2; ++kh) {
          float z[4][9];
          zcompute_k4n<96,64,9>(Pt + OFF_121, xd, o, kh, z);
#pragma unroll
          for (int e = 0; e < 10; ++e) {
            const float* ph = &sphi[e*12];
            const float* rr = ph + kh*4;
            float s[9];
#pragma unroll
            for (int m = 0; m < 9; ++m) s[m] = kdot4n<9>(z, m, rr);
            const float q0 = ph[8], q1 = ph[9], q2 = ph[10];
            float* pb = &psis[e*576 + t];
            pb[0]   += q0*s[0] + q1*s[1] + q2*s[2];
            pb[192] += q0*s[3] + q1*s[4] + q2*s[5];
            pb[384] += q0*s[6] + q1*s[7] + q2*s[8];
          }
        }
        {
          float z[8][3];
          zcompute<96,96,3>(Pt + OFF_211, xv, o, z);
#pragma unroll
          for (int e = 0; e < 10; ++e) {
            const float* ph = &sphi[e*12];
            const float tt = ph[8]*kdot<3>(z,0,ph) + ph[9]*kdot<3>(z,1,ph) + ph[10]*kdot<3>(z,2,ph);
            float* pb = &psis[e*576 + t];
            pb[0] += ph[8]*tt; pb[192] += ph[9]*tt; pb[384] += ph[10]*tt;
          }
        }
        {
          float z[8][3];
          zcompute<96,96,3>(Pt + OFF_111, xv, o, z);
#pragma unroll
          for (int e = 0; e < 10; ++e) {
            const float* ph = &sphi[e*12];
            const float s0 = kdot<3>(z,0,ph), s1 = kdot<3>(z,1,ph), s2 = kdot<3>(z,2,ph);
            const float q0 = ph[8], q1 = ph[9], q2 = ph[10];
            float* pb = &psis[e*576 + t];
            pb[0]   += q1*s2 - q2*s1;
            pb[192] += q2*s0 - q0*s2;
            pb[384] += q0*s1 - q1*s0;
          }
        }
#pragma unroll
        for (int e = 0; e < 10; ++e) {
          if (b0 + e < d) {
            const size_t bb = (size_t)(off0 + b0 + e)*576 + l*288 + o*3;
            const float* pb = &psis[e*576 + t];
            psiV[bb+0] = f2bf(pb[0]); psiV[bb+1] = f2bf(pb[192]); psiV[bb+2] = f2bf(pb[384]);
          }
        }
      }
    }
  } else {
    // ---------------- pass D: 128 active thr, window 5 ----------------
    const bool act = (t < 128);
    const int o = t & 63, l = (t >> 6) & 1;   // clamped for surplus lanes
    const float* xa = &sm[F1_XA + l*128];
    const float* xv = &sm[F1_XV + l*288];
    const float* xd = &sm[F1_XD + l*576];
    float* sphi = &sm[F1_TOT];            // 60
    float* psis = &sm[F1_TOT + 60];       // [5][128][9]

    const int nw = (d + 4) / 5;
    for (int w = 0; w < nw; ++w) {
      const int b0 = w * 5;
      __syncthreads();
      if (t < 60) {
        const int s = t / 12, f = t % 12;
        sphi[t] = (b0 + s < d) ? phi[(size_t)(off0 + b0 + s)*12 + f] : 0.f;
      }
      __syncthreads();

      if (act) {
        {
          float z[4][9];
          zcompute_k4n<64,64,9>(Pt + OFF_022, xd, o, 0, z);
#pragma unroll
          for (int e = 0; e < 5; ++e) {
            const float* rr = &sphi[e*12];
            float* pb = &psis[(e*128 + t)*9];
#pragma unroll
            for (int m = 0; m < 9; ++m) pb[m] = kdot4n<9>(z, m, rr);
          }
        }
        {
          float z[4][9];
          zcompute_k4n<64,64,9>(Pt + OFF_022, xd, o, 1, z);
#pragma unroll
          for (int e = 0; e < 5; ++e) {
            const float* rr = &sphi[e*12] + 4;
            float* pb = &psis[(e*128 + t)*9];
#pragma unroll
            for (int m = 0; m < 9; ++m) pb[m] += kdot4n<9>(z, m, rr);
          }
        }
        {
          float z[8][1];
          zcompute<64,128,1>(Pt + OFF_202, xa, o, z);
#pragma unroll
          for (int e = 0; e < 5; ++e) {
            const float* ph = &sphi[e*12];
            const float s0 = kdot<1>(z, 0, ph);
            const float q0 = ph[8], q1 = ph[9], q2 = ph[10];
            float* pb = &psis[(e*128 + t)*9];
            pb[0] += q0*q0*s0; pb[1] += q0*q1*s0; pb[2] += q0*q2*s0;
            pb[3] += q1*q0*s0; pb[4] += q1*q1*s0; pb[5] += q1*q2*s0;
            pb[6] += q2*q0*s0; pb[7] += q2*q1*s0; pb[8] += q2*q2*s0;
          }
        }
        {
          float z[8][3];
          zcompute<64,96,3>(Pt + OFF_112, xv, o, z);
#pragma unroll
          for (int e = 0; e < 5; ++e) {
            const float* ph = &sphi[e*12];
            const float s0 = kdot<3>(z,0,ph), s1 = kdot<3>(z,1,ph), s2 = kdot<3>(z,2,ph);
            const float q0 = ph[8], q1 = ph[9], q2 = ph[10];
            float* pb = &psis[(e*128 + t)*9];
            pb[0] += q0*s0; pb[1] += q0*s1; pb[2] += q0*s2;
            pb[3] += q1*s0; pb[4] += q1*s1; pb[5] += q1*s2;
            pb[6] += q2*s0; pb[7] += q2*s1; pb[8] += q2*s2;
          }
        }
#pragma unroll
        for (int kh = 0; kh < 2; ++kh) {
          float z[4][9];
          zcompute_k4n<64,64,9>(Pt + OFF_222, xd, o, kh, z);
#pragma unroll
          for (int e = 0; e < 5; ++e) {
            const float* ph = &sphi[e*12];
            const float* rr = ph + kh*4;
            float s[9];
#pragma unroll
            for (int m = 0; m < 9; ++m) s[m] = kdot4n<9>(z, m, rr);
            const float q0 = ph[8], q1 = ph[9], q2 = ph[10];
            const float u0 = q0*s[0] + q1*s[3] + q2*s[6];
            const float u1 = q0*s[1] + q1*s[4] + q2*s[7];
            const float u2 = q0*s[2] + q1*s[5] + q2*s[8];
            float* pb = &psis[(e*128 + t)*9];
            pb[0] += q0*u0; pb[1] += q0*u1; pb[2] += q0*u2;
            pb[3] += q1*u0; pb[4] += q1*u1; pb[5] += q1*u2;
            pb[6] += q2*u0; pb[7] += q2*u1; pb[8] += q2*u2;
          }
        }
        {
          float z[8][3];
          zcompute<64,96,3>(Pt + OFF_212, xv, o, z);
#pragma unroll
          for (int e = 0; e < 5; ++e) {
            const float* ph = &sphi[e*12];
            const float s0 = kdot<3>(z,0,ph), s1 = kdot<3>(z,1,ph), s2 = kdot<3>(z,2,ph);
            const float q0 = ph[8], q1 = ph[9], q2 = ph[10];
            const float c0 = q1*s2 - q2*s1;
            const float c1 = q2*s0 - q0*s2;
            const float c2 = q0*s1 - q1*s0;
            float* pb = &psis[(e*128 + t)*9];
            pb[0] += c0*q0; pb[1] += c0*q1; pb[2] += c0*q2;
            pb[3] += c1*q0; pb[4] += c1*q1; pb[5] += c1*q2;
            pb[6] += c2*q0; pb[7] += c2*q1; pb[8] += c2*q2;
          }
        }
#pragma unroll
        for (int e = 0; e < 5; ++e) {
          if (b0 + e < d) {
            const float* pb = &psis[(e*128 + t)*9];
            unsigned short* bp = &psiD[(size_t)(off0 + b0 + e)*1152 + t*9];
#pragma unroll
            for (int j = 0; j < 9; ++j) bp[j] = f2bf(pb[j]);
          }
        }
      }
    }
  }
}

// ---------------------------------------------------------------------------
// FUSED edge MLPs: grid 15000, 256 thr.  b%3==0 -> mlp_a (5000 blocks,
// 16 combos); else -> mlp_v (10000 blocks, 8 combos, 192 active thr).
// NO early returns: barriers at block scope, work guarded by `act`.
// ---------------------------------------------------------------------------
__global__ __launch_bounds__(256, 3) void mlp_fused_kernel(
    unsigned short* __restrict__ psiA, unsigned short* __restrict__ psiV,
    const float* __restrict__ Wdt,
    const float* __restrict__ W1t, const float* __restrict__ b1,
    const float* __restrict__ W2t, const float* __restrict__ b2,
    const float* __restrict__ W3t, const float* __restrict__ b3,
    const float* __restrict__ Vdt, const float* __restrict__ V1t,
    const float* __restrict__ V2t, const float* __restrict__ V3t)
{
  __shared__ float sm[11520];   // max(a:10240, v:11520) floats = 46080 B
  const int b = blockIdx.x;
  const int t = threadIdx.x;

  if (b % 3 == 0) {
    // ---------------- mlp_a: 16 combos ----------------
    const int cbase = (b / 3) * 16;
    float* PA = sm;            // [16][128]
    float* H1 = sm + 2048;     // [16][256]
    float* H2 = sm + 6144;     // [16][256]

    for (int q = t; q < 2048; q += 256)
      PA[q] = bf2f(psiA[(size_t)cbase*128 + q]);
    __syncthreads();
    {
      const int p0 = (t & 63) * 4, j0 = (t >> 6) * 4;
      float acc[4][4];
#pragma unroll
      for (int r = 0; r < 4; ++r)
#pragma unroll
        for (int j = 0; j < 4; ++j) acc[r][j] = 0.f;
      for (int c = 0; c < 128; c += 4) {
        float4 wv[4];
#pragma unroll
        for (int cc = 0; cc < 4; ++cc) wv[cc] = *(const float4*)&W1t[(size_t)(c+cc)*256 + p0];
#pragma unroll
        for (int j = 0; j < 4; ++j) {
          const float4 x = *(const float4*)&PA[(j0+j)*128 + c];
          acc[0][j] += wv[0].x*x.x + wv[1].x*x.y + wv[2].x*x.z + wv[3].x*x.w;
          acc[1][j] += wv[0].y*x.x + wv[1].y*x.y + wv[2].y*x.z + wv[3].y*x.w;
          acc[2][j] += wv[0].z*x.x + wv[1].z*x.y + wv[2].z*x.z + wv[3].z*x.w;
          acc[3][j] += wv[0].w*x.x + wv[1].w*x.y + wv[2].w*x.z + wv[3].w*x.w;
        }
      }
      const float bb0 = b1[p0], bb1 = b1[p0+1], bb2 = b1[p0+2], bb3 = b1[p0+3];
#pragma unroll
      for (int j = 0; j < 4; ++j) {
        float4 v; v.x = lrelu(acc[0][j]+bb0); v.y = lrelu(acc[1][j]+bb1);
        v.z = lrelu(acc[2][j]+bb2); v.w = lrelu(acc[3][j]+bb3);
        *(float4*)&H1[(j0+j)*256 + p0] = v;
      }
    }
    __syncthreads();
    {
      const int p0 = (t & 63) * 4, j0 = (t >> 6) * 4;
      float acc[4][4];
#pragma unroll
      for (int r = 0; r < 4; ++r)
#pragma unroll
        for (int j = 0; j < 4; ++j) acc[r][j] = 0.f;
      for (int c = 0; c < 256; c += 4) {
        float4 wv[4];
#pragma unroll
        for (int cc = 0; cc < 4; ++cc) wv[cc] = *(const float4*)&W2t[(size_t)(c+cc)*256 + p0];
#pragma unroll
        for (int j = 0; j < 4; ++j) {
          const float4 x = *(const float4*)&H1[(j0+j)*256 + c];
          acc[0][j] += wv[0].x*x.x + wv[1].x*x.y + wv[2].x*x.z + wv[3].x*x.w;
          acc[1][j] += wv[0].y*x.x + wv[1].y*x.y + wv[2].y*x.z + wv[3].y*x.w;
          acc[2][j] += wv[0].z*x.x + wv[1].z*x.y + wv[2].z*x.z + wv[3].z*x.w;
          acc[3][j] += wv[0].w*x.x + wv[1].w*x.y + wv[2].w*x.z + wv[3].w*x.w;
        }
      }
      const float bb0 = b2[p0], bb1 = b2[p0+1], bb2 = b2[p0+2], bb3 = b2[p0+3];
#pragma unroll
      for (int j = 0; j < 4; ++j) {
        float4 v; v.x = lrelu(acc[0][j]+bb0); v.y = lrelu(acc[1][j]+bb1);
        v.z = lrelu(acc[2][j]+bb2); v.w = lrelu(acc[3][j]+bb3);
        *(float4*)&H2[(j0+j)*256 + p0] = v;
      }
    }
    __syncthreads();
    {
      const int p0 = (t & 63) * 2, j0 = (t >> 6) * 4;
      float acc[2][4];
#pragma unroll
      for (int r = 0; r < 2; ++r)
#pragma unroll
        for (int j = 0; j < 4; ++j) acc[r][j] = 0.f;
      for (int c = 0; c < 128; c += 4) {
        float2 wv[4];
#pragma unroll
        for (int cc = 0; cc < 4; ++cc) wv[cc] = *(const float2*)&Wdt[(size_t)(c+cc)*128 + p0];
#pragma unroll
        for (int j = 0; j < 4; ++j) {
          const float4 x = *(const float4*)&PA[(j0+j)*128 + c];
          acc[0][j] += wv[0].x*x.x + wv[1].x*x.y + wv[2].x*x.z + wv[3].x*x.w;
          acc[1][j] += wv[0].y*x.x + wv[1].y*x.y + wv[2].y*x.z + wv[3].y*x.w;
        }
      }
      for (int c = 0; c < 256; c += 4) {
        float2 wv[4];
#pragma unroll
        for (int cc = 0; cc < 4; ++cc) wv[cc] = *(const float2*)&W3t[(size_t)(c+cc)*128 + p0];
#pragma unroll
        for (int j = 0; j < 4; ++j) {
          const float4 x = *(const float4*)&H2[(j0+j)*256 + c];
          acc[0][j] += wv[0].x*x.x + wv[1].x*x.y + wv[2].x*x.z + wv[3].x*x.w;
          acc[1][j] += wv[0].y*x.x + wv[1].y*x.y + wv[2].y*x.z + wv[3].y*x.w;
        }
      }
      const float bb0 = b3[p0], bb1 = b3[p0+1];
#pragma unroll
      for (int j = 0; j < 4; ++j) {
        const float o0 = acc[0][j] + bb0 + PA[(j0+j)*128 + p0];
        const float o1 = acc[1][j] + bb1 + PA[(j0+j)*128 + p0 + 1];
        psiA[(size_t)(cbase + j0 + j)*128 + p0]     = f2bf(o0);
        psiA[(size_t)(cbase + j0 + j)*128 + p0 + 1] = f2bf(o1);
      }
    }
  } else {
    // ---------------- mlp_v: 8 combos, 192 active thr ----------------
    const bool act = (t < 192);
    const int cbase = (b - b/3 - 1) * 8;
    float* PV  = sm;            // [8][288]
    float* HV  = sm + 2304;     // [8][576]
    float* HV2 = sm + 6912;     // [8][576]

    for (int q = t; q < 2304; q += 256) {   // all 256 threads stage
      const int j = q / 288, r = q % 288, i = r / 96, o = r % 96;
      PV[j*288 + i*96 + o] = bf2f(psiV[(size_t)(cbase + j)*288 + o*3 + i]);
    }
    __syncthreads();
    if (act) {
      const int p0 = (t % 96) * 2, j0 = (t / 96) * 4;
      float acc[2][4][3];
#pragma unroll
      for (int r = 0; r < 2; ++r)
#pragma unroll
        for (int j = 0; j < 4; ++j) { acc[r][j][0]=0.f; acc[r][j][1]=0.f; acc[r][j][2]=0.f; }
      for (int c = 0; c < 96; c += 4) {
        float2 wv[4];
#pragma unroll
        for (int cc = 0; cc < 4; ++cc) wv[cc] = *(const float2*)&V1t[(size_t)(c+cc)*192 + p0];
#pragma unroll
        for (int j = 0; j < 4; ++j)
#pragma unroll
          for (int i = 0; i < 3; ++i) {
            const float4 x = *(const float4*)&PV[(j0+j)*288 + i*96 + c];
            acc[0][j][i] += wv[0].x*x.x + wv[1].x*x.y + wv[2].x*x.z + wv[3].x*x.w;
            acc[1][j][i] += wv[0].y*x.x + wv[1].y*x.y + wv[2].y*x.z + wv[3].y*x.w;
          }
      }
      float scl[2][4];
#pragma unroll
      for (int r = 0; r < 2; ++r)
#pragma unroll
        for (int j = 0; j < 4; ++j) {
          const float nn = sqrtf(acc[r][j][0]*acc[r][j][0] + acc[r][j][1]*acc[r][j][1]
                               + acc[r][j][2]*acc[r][j][2] + 1e-12f);
          scl[r][j] = (2.f / (1.f + expf(-nn)) - 1.f) / nn;
        }
#pragma unroll
      for (int j = 0; j < 4; ++j)
#pragma unroll
        for (int i = 0; i < 3; ++i) {
          float2 v;
          v.x = acc[0][j][i]*scl[0][j]; v.y = acc[1][j][i]*scl[1][j];
          *(float2*)&HV[(j0+j)*576 + i*192 + p0] = v;
        }
    }
    __syncthreads();
    if (act) {
      const int p0 = (t % 96) * 2, j0 = (t / 96) * 4;
      float acc[2][4][3];
#pragma unroll
      for (int r = 0; r < 2; ++r)
#pragma unroll
        for (int j = 0; j < 4; ++j) { acc[r][j][0]=0.f; acc[r][j][1]=0.f; acc[r][j][2]=0.f; }
      for (int c = 0; c < 192; c += 4) {
        float2 wv[4];
#pragma unroll
        for (int cc = 0; cc < 4; ++cc) wv[cc] = *(const float2*)&V2t[(size_t)(c+cc)*192 + p0];
#pragma unroll
        for (int j = 0; j < 4; ++j)
#pragma unroll
          for (int i = 0; i < 3; ++i) {
            const float4 x = *(const float4*)&HV[(j0+j)*576 + i*192 + c];
            acc[0][j][i] += wv[0].x*x.x + wv[1].x*x.y + wv[2].x*x.z + wv[3].x*x.w;
            acc[1][j][i] += wv[0].y*x.x + wv[1].y*x.y + wv[2].y*x.z + wv[3].y*x.w;
          }
      }
      float scl[2][4];
#pragma unroll
      for (int r = 0; r < 2; ++r)
#pragma unroll
        for (int j = 0; j < 4; ++j) {
          const float nn = sqrtf(acc[r][j][0]*acc[r][j][0] + acc[r][j][1]*acc[r][j][1]
                               + acc[r][j][2]*acc[r][j][2] + 1e-12f);
          scl[r][j] = (2.f / (1.f + expf(-nn)) - 1.f) / nn;
        }
#pragma unroll
      for (int j = 0; j < 4; ++j)
#pragma unroll
        for (int i = 0; i < 3; ++i) {
          float2 v;
          v.x = acc[0][j][i]*scl[0][j]; v.y = acc[1][j][i]*scl[1][j];
          *(float2*)&HV2[(j0+j)*576 + i*192 + p0] = v;
        }
    }
    __syncthreads();
    if (act) {
      const int p0 = t % 96, j0 = (t / 96) * 4;
      float acc[4][3];
#pragma unroll
      for (int j = 0; j < 4; ++j) { acc[j][0]=0.f; acc[j][1]=0.f; acc[j][2]=0.f; }
      for (int c = 0; c < 96; c += 4) {
        float wv[4];
#pragma unroll
        for (int cc = 0; cc < 4; ++cc) wv[cc] = Vdt[(size_t)(c+cc)*96 + p0];
#pragma unroll
        for (int j = 0; j < 4; ++j)
#pragma unroll
          for (int i = 0; i < 3; ++i) {
            const float4 x = *(const float4*)&PV[(j0+j)*288 + i*96 + c];
            acc[j][i] += wv[0]*x.x + wv[1]*x.y + wv[2]*x.z + wv[3]*x.w;
          }
      }
      for (int c = 0; c < 192; c += 4) {
        float wv[4];
#pragma unroll
        for (int cc = 0; cc < 4; ++cc) wv[cc] = V3t[(size_t)(c+cc)*96 + p0];
#pragma unroll
        for (int j = 0; j < 4; ++j)
#pragma unroll
          for (int i = 0; i < 3; ++i) {
            const float4 x = *(const float4*)&HV2[(j0+j)*576 + i*192 + c];
            acc[j][i] += wv[0]*x.x + wv[1]*x.y + wv[2]*x.z + wv[3]*x.w;
          }
      }
#pragma unroll
      for (int j = 0; j < 4; ++j)
#pragma unroll
        for (int i = 0; i < 3; ++i) {
          const float v = acc[j][i] + PV[(j0+j)*288 + i*96 + p0];
          psiV[(size_t)(cbase + j0 + j)*288 + p0*3 + i] = f2bf(v);
        }
    }
  }
}

// ---------------------------------------------------------------------------
// Gather (by src) + fused output projection. Block per src atom, 256 thr.
// ---------------------------------------------------------------------------
__global__ __launch_bounds__(256, 2) void gather_out_kernel(
    const int* __restrict__ soff, const int* __restrict__ sperm,
    const unsigned short* __restrict__ psiA, const unsigned short* __restrict__ psiV,
    const unsigned short* __restrict__ psiD,
    const float* __restrict__ Wa, const float* __restrict__ Wv, const float* __restrict__ Wd,
    float* __restrict__ out)
{
  __shared__ float bs[1984];
  const int n = blockIdx.x, t = threadIdx.x;
  const int s0 = soff[n], s1 = soff[n + 1];
  float acc[8];
#pragma unroll
  for (int u = 0; u < 8; ++u) acc[u] = 0.f;
  for (int p2 = s0; p2 < s1; ++p2) {
    const int slot = sperm[p2];
    const unsigned short* ra = psiA + (size_t)slot * 256;
    const unsigned short* rv = psiV + (size_t)slot * 576;
    const unsigned short* rd = psiD + (size_t)slot * 1152;
#pragma unroll
    for (int u = 0; u < 8; ++u) {
      const int v = t + 256 * u;
      if (v < 256)        acc[u] += bf2f(ra[v]);
      else if (v < 832)   acc[u] += bf2f(rv[v - 256]);
      else if (v < 1984)  acc[u] += bf2f(rd[v - 832]);
    }
  }
#pragma unroll
  for (int u = 0; u < 8; ++u) {
    const int v = t + 256 * u;
    if (v < 1984) bs[v] = acc[u];
  }
  __syncthreads();
  if (t < 128) {
    const float* W = &Wa[(size_t)t * 256];
    float a = 0.f;
    for (int c = 0; c < 256; c += 4) a += dot4f(*(const float4*)&W[c], *(const float4*)&bs[c]);
    out[(size_t)n*128 + t] = a;
  }
  if (t < 96) {
    const float* W = &Wv[(size_t)t * 192];
    float a0 = 0.f, a1 = 0.f, a2 = 0.f;
    for (int c = 0; c < 192; ++c) {
      const float w = W[c]; const float* x = &bs[256 + c*3];
      a0 = fmaf(w, x[0], a0); a1 = fmaf(w, x[1], a1); a2 = fmaf(w, x[2], a2);
    }
    float* d = &out[OUT_V + ((size_t)n*96 + t)*3];
    d[0] = a0; d[1] = a1; d[2] = a2;
  }
  if (t < 64) {
    const float* W = &Wd[(size_t)t * 128];
    float a[9] = {0,0,0,0,0,0,0,0,0};
    for (int c = 0; c < 128; ++c) {
      const float w = W[c]; const float* x = &bs[832 + c*9];
#pragma unroll
      for (int j = 0; j < 9; ++j) a[j] = fmaf(w, x[j], a[j]);
    }
    float* d = &out[OUT_D + ((size_t)n*64 + t)*9];
#pragma unroll
    for (int j = 0; j < 9; ++j) d[j] = a[j];
  }
}

// ---------------------------------------------------------------------------
// Host entry
// ---------------------------------------------------------------------------
extern "C" void kernel_launch(void* const* d_in, const int* in_sizes, int n_in,
                              void* d_out, int out_size, void* d_ws, size_t ws_size,
                              hipStream_t stream) {
  (void)in_sizes; (void)n_in; (void)out_size; (void)ws_size;
  const int*   src  = (const int*)d_in[0];
  const int*   dst  = (const int*)d_in[1];
  const float* r_ij = (const float*)d_in[2];
  const float* x_a  = (const float*)d_in[3];
  const float* x_v  = (const float*)d_in[4];
  const float* x_d  = (const float*)d_in[5];
  const float* P[13];
  for (int i = 0; i < 13; ++i) P[i] = (const float*)d_in[6 + i];
  const float* W_in_a  = (const float*)d_in[19];
  const float* W_in_v  = (const float*)d_in[20];
  const float* W_in_d  = (const float*)d_in[21];
  const float* W_out_a = (const float*)d_in[22];
  const float* W_out_v = (const float*)d_in[23];
  const float* W_out_d = (const float*)d_in[24];
  const float* Wd_a = (const float*)d_in[25];
  const float* W1   = (const float*)d_in[26];
  const float* b1   = (const float*)d_in[27];
  const float* W2   = (const float*)d_in[28];
  const float* b2   = (const float*)d_in[29];
  const float* W3   = (const float*)d_in[30];
  const float* b3   = (const float*)d_in[31];
  const float* Vd   = (const float*)d_in[32];
  const float* V1   = (const float*)d_in[33];
  const float* V2   = (const float*)d_in[34];
  const float* V3   = (const float*)d_in[35];

  float* ws = (float*)d_ws;
  float* Pt = ws;
  int*   ib = (int*)(ws + INT_OFF);
  unsigned short* psiA = (unsigned short*)(ws + PSIA_OFF);
  unsigned short* psiV = (unsigned short*)(ws + PSIV_OFF);
  unsigned short* psiD = (unsigned short*)(ws + PSID_OFF);
  float* ot = (float*)d_out;   // head of d_out = transposed-weight scratch

  // 1) fused transposes (2 launches instead of 21)
  P13 ps; for (int i = 0; i < 13; ++i) ps.p[i] = P[i];
  transP_all_kernel<<<(111616 + 255) / 256, 256, 0, stream>>>(ps, Pt);
  P8 pw;
  pw.p[0] = W1; pw.p[1] = W2; pw.p[2] = W3; pw.p[3] = Wd_a;
  pw.p[4] = V1; pw.p[5] = V2; pw.p[6] = V3; pw.p[7] = Vd;
  transW_all_kernel<<<(230400 + 255) / 256, 256, 0, stream>>>(pw, ot);

  // 2) zero sort counters
  hipMemsetAsync(ib, 0, 20000 * sizeof(int), stream);

  // 3) sorts + per-edge encodings (4 launches)
  const int egrid = (NE + 255) / 256;
  hist2_kernel<<<egrid, 256, 0, stream>>>(dst, src, ib + ICNT, ib + SCNT);
  scan2_kernel<<<2, 256, 0, stream>>>(ib + ICNT, ib + IOFF, ib + SCNT, ib + SOFF);
  sort_scatter_kernel<<<egrid, 256, 0, stream>>>(dst, ib + IOFF, ib + ICUR, ib + IEIDX, ib + ISLOT);
  ssort_phi_kernel<<<2 * egrid, 256, 0, stream>>>(src, ib + ISLOT, ib + SOFF, ib + SCUR,
                                                  ib + SPERM, ib + IEIDX, r_ij, ws + PHI_OFF);

  // 4) input projections
  proj_in_kernel<<<NA, 256, 0, stream>>>(x_a, x_v, x_d, W_in_a, W_in_v, W_in_d,
                                         ws + A_OFF, ws + V_OFF, ws + D_OFF);

  // 5) FUSED message passes: a/v/d blocks co-resident (type = blockIdx%3)
  pass_fused_kernel<<<3 * NA, 256, 0, stream>>>(ib + IOFF, ws + PHI_OFF, Pt,
                                                ws + A_OFF, ws + V_OFF, ws + D_OFF,
                                                psiA, psiV, psiD);

  // 6) FUSED edge MLPs (a: 5000 blocks, v: 10000 blocks)
  mlp_fused_kernel<<<15000, 256, 0, stream>>>(psiA, psiV,
                                              ot + WTD, ot + WT1, b1, ot + WT2, b2, ot + WT3, b3,
                                              ot + VTD, ot + VT1, ot + VT2, ot + VT3);

  // 7) gather by src + fused output projection (overwrites all of d_out)
  gather_out_kernel<<<NA, 256, 0, stream>>>(ib + SOFF, ib + SPERM,
                                            psiA, psiV, psiD,
                                            W_out_a, W_out_v, W_out_d, (float*)d_out);
}

// Round 10
// 3303.702 us; speedup vs baseline: 1.9134x; 1.1318x over previous
//
#include <hip/hip_runtime.h>
#include <hip/hip_bf16.h>

// ---------------------------------------------------------------------------
// Problem constants
// ---------------------------------------------------------------------------
#define NA 5000           // atoms
#define NE 40000          // edges
// DA=128, DV=96, DD=64, NL=8, L=2

// ---------------------------------------------------------------------------
// Workspace layout (float indices)
// ---------------------------------------------------------------------------
static const int POFF[13] = {0, 131072, 229376, 294912, 368640, 466944, 516096,
                             589824, 663552, 696320, 761856, 811008, 843776};
#define A_OFF    892928          // a  [2][NA][128] fp32
#define V_OFF    2172928         // v  [2][NA][288] fp32
#define D_OFF    5052928         // d  [2][NA][576] fp32
#define PHI_OFF  10812928        // [NE][12] fp32
#define PSIA_OFF 11292928        // bf16 [NE][256]
#define PSIV_OFF 16412928        // bf16 [NE][576]
#define PSID_OFF 27932928        // bf16 [NE][1152]
#define INT_OFF  50972928
// int region (indices into (int*)(ws + INT_OFF))
#define ICNT  0        // [5000]
#define ICUR  5000     // [5000]
#define SCNT  10000    // [5000]
#define SCUR  15000    // [5000]
#define IOFF  20000    // [5001]
#define SOFF  25008    // [5001]
#define IEIDX 30016    // [NE]
#define ISLOT 70016    // [NE]
#define SPERM 110016   // [NE]

// output layout (floats)
#define OUT_V 640000
#define OUT_D 2080000

// transposed-MLP-weight scratch at the HEAD of d_out (free until gather).
#define WT1 0          // [128][256]
#define WT2 32768      // [256][256]
#define WT3 98304      // [256][128]
#define WTD 131072     // [128][128]
#define VT1 147456     // [96][192]
#define VT2 165888     // [192][192]
#define VT3 202752     // [192][96]
#define VTD 221184     // [96][96]   -> ends 230400

#define OFF_000 POFF[0]
#define OFF_110 POFF[1]
#define OFF_220 POFF[2]
#define OFF_011 POFF[3]
#define OFF_101 POFF[4]
#define OFF_121 POFF[5]
#define OFF_211 POFF[6]
#define OFF_111 POFF[7]
#define OFF_022 POFF[8]
#define OFF_202 POFF[9]
#define OFF_112 POFF[10]
#define OFF_222 POFF[11]
#define OFF_212 POFF[12]

__device__ __forceinline__ float dot4f(float4 a, float4 b) {
  return a.x*b.x + a.y*b.y + a.z*b.z + a.w*b.w;
}
__device__ __forceinline__ float lrelu(float x) { return x > 0.f ? x : 0.1f*x; }
__device__ __forceinline__ float bf2f(unsigned short u) {
  union { unsigned int i; float f; } x; x.i = ((unsigned int)u) << 16; return x.f;
}
__device__ __forceinline__ unsigned short f2bf(float f) {
  union { unsigned int i; float f; } x; x.f = f;
  unsigned int r = x.i + 0x7FFFu + ((x.i >> 16) & 1u);
  return (unsigned short)(r >> 16);
}

struct P13 { const float* p[13]; };
struct P8  { const float* p[8]; };

// ---------------------------------------------------------------------------
// Fused P transpose: all 13 tensors [O][8][C] -> [C][O][8] in one launch.
// ---------------------------------------------------------------------------
__global__ __launch_bounds__(256) void transP_all_kernel(P13 ps, float* __restrict__ Pt)
{
  static const int Od[13] = {128,128,128, 96, 96, 96, 96, 96, 64, 64, 64, 64, 64};
  static const int Cd[13] = {128, 96, 64, 96,128, 64, 96, 96, 64,128, 96, 64, 96};
  static const int POF[13] = {0, 131072, 229376, 294912, 368640, 466944, 516096,
                              589824, 663552, 696320, 761856, 811008, 843776};
  static const int CUM[14] = {0,16384,28672,36864,46080,58368,64512,73728,
                              82944,87040,95232,101376,105472,111616};
  int idx = blockIdx.x * 256 + threadIdx.x;
  if (idx >= 111616) return;
  int i = 0;
  while (idx >= CUM[i+1]) ++i;
  const int r = idx - CUM[i];
  const int O = Od[i], C = Cd[i];
  const int o = r / C, c = r % C;
  const float* src = ps.p[i];
  float* dst = Pt + POF[i];
#pragma unroll
  for (int k = 0; k < 8; ++k)
    dst[((size_t)c * O + o) * 8 + k] = src[((size_t)o * 8 + k) * C + c];
}

// ---------------------------------------------------------------------------
// Fused MLP-weight transpose: 8 matrices [R][C] -> [C][R], packed at CUM[i].
// ---------------------------------------------------------------------------
__global__ __launch_bounds__(256) void transW_all_kernel(P8 ps, float* __restrict__ ot)
{
  static const int R[8]   = {256,256,128,128,192,192, 96, 96};
  static const int C[8]   = {128,256,256,128, 96,192,192, 96};
  static const int CUM[9] = {0,32768,98304,131072,147456,165888,202752,221184,230400};
  int idx = blockIdx.x * 256 + threadIdx.x;
  if (idx >= 230400) return;
  int i = 0;
  while (idx >= CUM[i+1]) ++i;
  const int r = idx - CUM[i];
  const int rr = r / C[i], cc = r % C[i];
  ot[(size_t)CUM[i] + (size_t)cc * R[i] + rr] = ps.p[i][r];
}

// ---------------------------------------------------------------------------
// Counting sorts (merged where dependency-free)
// ---------------------------------------------------------------------------
__global__ __launch_bounds__(256) void hist2_kernel(
    const int* __restrict__ dstk, const int* __restrict__ srck,
    int* __restrict__ cntd, int* __restrict__ cnts)
{
  int e = blockIdx.x * 256 + threadIdx.x;
  if (e < NE) { atomicAdd(&cntd[dstk[e]], 1); atomicAdd(&cnts[srck[e]], 1); }
}

__global__ __launch_bounds__(256) void scan2_kernel(
    const int* __restrict__ cnt0, int* __restrict__ off0,
    const int* __restrict__ cnt1, int* __restrict__ off1)
{
  const int* cnt = (blockIdx.x == 0) ? cnt0 : cnt1;
  int* off       = (blockIdx.x == 0) ? off0 : off1;
  __shared__ int part[256];
  const int t = threadIdx.x;
  int loc[20]; int s = 0;
#pragma unroll
  for (int i = 0; i < 20; ++i) {
    int idx = t * 20 + i;
    int v = (idx < NA) ? cnt[idx] : 0;
    loc[i] = v; s += v;
  }
  part[t] = s; __syncthreads();
  for (int ofs = 1; ofs < 256; ofs <<= 1) {
    int v = (t >= ofs) ? part[t - ofs] : 0;
    __syncthreads();
    part[t] += v;
    __syncthreads();
  }
  int run = part[t] - s;   // exclusive prefix
#pragma unroll
  for (int i = 0; i < 20; ++i) {
    int idx = t * 20 + i;
    if (idx < NA) off[idx] = run;
    run += loc[i];
  }
  if (t == 255) off[NA] = run;
}

__global__ __launch_bounds__(256) void sort_scatter_kernel(
    const int* __restrict__ dst, const int* __restrict__ off,
    int* __restrict__ cur, int* __restrict__ eidx, int* __restrict__ islot)
{
  int e = blockIdx.x * 256 + threadIdx.x;
  if (e >= NE) return;
  int d = dst[e];
  int pos = off[d] + atomicAdd(&cur[d], 1);
  eidx[pos] = e;
  islot[e] = pos;
}

// ssort + phi fused (both depend only on sort_scatter outputs)
__global__ __launch_bounds__(256) void ssort_phi_kernel(
    const int* __restrict__ src, const int* __restrict__ islot,
    const int* __restrict__ soff, int* __restrict__ scur, int* __restrict__ sperm,
    const int* __restrict__ eidx, const float* __restrict__ r_ij, float* __restrict__ phi)
{
  const int B = (NE + 255) / 256;
  if ((int)blockIdx.x < B) {
    int e = blockIdx.x * 256 + threadIdx.x;
    if (e >= NE) return;
    int s = src[e];
    int pos = soff[s] + atomicAdd(&scur[s], 1);
    sperm[pos] = islot[e];
  } else {
    int p = (blockIdx.x - B) * 256 + threadIdx.x;
    if (p >= NE) return;
    int e = eidx[p];
    const float rx = r_ij[e*3+0], ry = r_ij[e*3+1], rz = r_ij[e*3+2];
    const float r2 = rx*rx + ry*ry + rz*rz;
    const float r = sqrtf(r2 + 1e-12f);
#pragma unroll
    for (int k = 0; k < 8; ++k) {
      const float z = 7.f*r - (float)k;
      phi[(size_t)p*12 + k] = expf(-0.5f*z*z);
    }
    const float nn = sqrtf(49.f*r2 + 1e-12f);
    const float sc = (2.f / (1.f + expf(-nn)) - 1.f) / nn;
    phi[(size_t)p*12 + 8]  = 7.f*rx*sc;
    phi[(size_t)p*12 + 9]  = 7.f*ry*sc;
    phi[(size_t)p*12 + 10] = 7.f*rz*sc;
    phi[(size_t)p*12 + 11] = 0.f;
  }
}

// ---------------------------------------------------------------------------
// Input projection (per atom)
// ---------------------------------------------------------------------------
__global__ __launch_bounds__(256) void proj_in_kernel(
    const float* __restrict__ x_a, const float* __restrict__ x_v, const float* __restrict__ x_d,
    const float* __restrict__ Wa, const float* __restrict__ Wv, const float* __restrict__ Wd,
    float* __restrict__ a_ws, float* __restrict__ v_ws, float* __restrict__ d_ws)
{
  __shared__ float xs[992];
  const int n = blockIdx.x, t = threadIdx.x;
  for (int q = t; q < 128; q += 256) xs[q]       = x_a[(size_t)n*128 + q];
  for (int q = t; q < 288; q += 256) xs[128 + q] = x_v[(size_t)n*288 + q];
  for (int q = t; q < 576; q += 256) xs[416 + q] = x_d[(size_t)n*576 + q];
  __syncthreads();
  {
    const float* W = &Wa[(size_t)t * 128];
    float acc = 0.f;
    for (int c = 0; c < 128; c += 4) acc += dot4f(*(const float4*)&W[c], *(const float4*)&xs[c]);
    int l = t >> 7, o = t & 127;
    a_ws[((size_t)l*NA + n)*128 + o] = acc;
  }
  if (t < 192) {
    const float* W = &Wv[(size_t)t * 96];
    float a0 = 0.f, a1 = 0.f, a2 = 0.f;
    for (int c = 0; c < 96; ++c) {
      float w = W[c]; const float* x = &xs[128 + c*3];
      a0 = fmaf(w, x[0], a0); a1 = fmaf(w, x[1], a1); a2 = fmaf(w, x[2], a2);
    }
    int l = t / 96, o = t % 96;
    float* dstp = &v_ws[(((size_t)l*NA + n)*96 + o)*3];
    dstp[0] = a0; dstp[1] = a1; dstp[2] = a2;
  }
  if (t < 128) {
    const float* W = &Wd[(size_t)t * 64];
    float acc[9] = {0,0,0,0,0,0,0,0,0};
    for (int c = 0; c < 64; ++c) {
      float w = W[c]; const float* x = &xs[416 + c*9];
#pragma unroll
      for (int j = 0; j < 9; ++j) acc[j] = fmaf(w, x[j], acc[j]);
    }
    int l = t >> 6, o = t & 63;
    float* dstp = &d_ws[(((size_t)l*NA + n)*64 + o)*9];
#pragma unroll
    for (int j = 0; j < 9; ++j) dstp[j] = acc[j];
  }
}

// ---------------------------------------------------------------------------
// Z helpers.  Pt layout [C][O][8].
// ---------------------------------------------------------------------------
template<int O, int C, int NMU>
__device__ __forceinline__ void zcompute(const float* __restrict__ Pt,
    const float* __restrict__ xl, int o, float z[8][NMU])
{
#pragma unroll
  for (int k = 0; k < 8; ++k)
#pragma unroll
    for (int m = 0; m < NMU; ++m) z[k][m] = 0.f;
  const float* p = Pt + o * 8;
#pragma unroll 2
  for (int c = 0; c < C; ++c, p += O*8) {
    const float4 pa = *(const float4*)p;
    const float4 pb = *(const float4*)(p + 4);
#pragma unroll
    for (int m = 0; m < NMU; ++m) {
      const float xv = xl[c * NMU + m];
      z[0][m] = fmaf(pa.x, xv, z[0][m]);
      z[1][m] = fmaf(pa.y, xv, z[1][m]);
      z[2][m] = fmaf(pa.z, xv, z[2][m]);
      z[3][m] = fmaf(pa.w, xv, z[3][m]);
      z[4][m] = fmaf(pb.x, xv, z[4][m]);
      z[5][m] = fmaf(pb.y, xv, z[5][m]);
      z[6][m] = fmaf(pb.z, xv, z[6][m]);
      z[7][m] = fmaf(pb.w, xv, z[7][m]);
    }
  }
}

// half-k variant, generic NMU: z[4][NMU] for k range [kh*4, kh*4+4)
template<int O, int C, int NMU>
__device__ __forceinline__ void zcompute_k4n(const float* __restrict__ Pt,
    const float* __restrict__ xl, int o, int kh, float z[4][NMU])
{
#pragma unroll
  for (int k = 0; k < 4; ++k)
#pragma unroll
    for (int m = 0; m < NMU; ++m) z[k][m] = 0.f;
  const float* p = Pt + o * 8 + kh * 4;
#pragma unroll 2
  for (int c = 0; c < C; ++c, p += O*8) {
    const float4 pa = *(const float4*)p;
#pragma unroll
    for (int m = 0; m < NMU; ++m) {
      const float xv = xl[c*NMU + m];
      z[0][m] = fmaf(pa.x, xv, z[0][m]);
      z[1][m] = fmaf(pa.y, xv, z[1][m]);
      z[2][m] = fmaf(pa.z, xv, z[2][m]);
      z[3][m] = fmaf(pa.w, xv, z[3][m]);
    }
  }
}

template<int NMU>
__device__ __forceinline__ float kdot(const float z[8][NMU], int m, const float* rr) {
  float s = z[0][m] * rr[0];
#pragma unroll
  for (int k = 1; k < 8; ++k) s = fmaf(z[k][m], rr[k], s);
  return s;
}
template<int NMU>
__device__ __forceinline__ float kdot4n(const float z[4][NMU], int m, const float* rr) {
  float s = z[0][m] * rr[0];
#pragma unroll
  for (int k = 1; k < 4; ++k) s = fmaf(z[k][m], rr[k], s);
  return s;
}

// shared feature layout (floats), SINGLE atom, both l:
//   XA [l][128]=256 | XV [l][288]=576 | XD [l][576]=1152  -> 1984
#define F1_XA 0
#define F1_XV 256
#define F1_XD 832
#define F1_TOT 1984

template<int NT>
__device__ __forceinline__ void load_features1(float* sm, int t, int n,
    const float* __restrict__ a_ws, const float* __restrict__ v_ws, const float* __restrict__ d_ws)
{
  for (int q = t; q < 256; q += NT)
    sm[F1_XA + q] = a_ws[((size_t)(q>>7)*NA + n)*128 + (q & 127)];
  for (int q = t; q < 576; q += NT)
    sm[F1_XV + q] = v_ws[((size_t)(q/288)*NA + n)*288 + (q % 288)];
  for (int q = t; q < 1152; q += NT)
    sm[F1_XD + q] = d_ws[((size_t)(q/576)*NA + n)*576 + (q % 576)];
}

// ---------------------------------------------------------------------------
// FUSED message pass: grid 3*NA, 256 thr.  type = blockIdx%3.
// A: 256 thr (o x l), window 16.
// V: 192 active thr (o x l), window 14 (round-7 was 12; wider = fewer
//    z-recomputes, E[windows] 1.07->1.04).
// D: 128 active thr (o x l), window 7 (round-7 was 6; E[windows] 1.75->1.55,
//    -11% of the heaviest z-work).
// LDS union = max(a:6272, v:10216, d:10132) = 10216 fl = 40864 B -> 4 blk/CU.
// (Round-9 narrow-window experiment REVERTED: work reduction > occupancy.)
// ---------------------------------------------------------------------------
__global__ __launch_bounds__(256, 3) void pass_fused_kernel(
    const int* __restrict__ off, const float* __restrict__ phi,
    const float* __restrict__ Pt,
    const float* __restrict__ a_ws, const float* __restrict__ v_ws, const float* __restrict__ d_ws,
    unsigned short* __restrict__ psiA, unsigned short* __restrict__ psiV,
    unsigned short* __restrict__ psiD)
{
  __shared__ float sm[10216];
  const int b = blockIdx.x;
  const int type = b % 3;
  const int n = b / 3;
  const int t = threadIdx.x;
  const int off0 = off[n], off1 = off[n + 1];
  const int d = off1 - off0;
  if (d == 0) return;   // uniform across block: no thread has hit a barrier

  load_features1<256>(sm, t, n, a_ws, v_ws, d_ws);   // all 256 threads help

  if (type == 0) {
    // ---------------- pass A: 256 thr, window 16 ----------------
    const int o = t & 127, l = t >> 7;
    const float* xa = &sm[F1_XA + l*128];
    const float* xv = &sm[F1_XV + l*288];
    const float* xd = &sm[F1_XD + l*576];
    float* sphi = &sm[F1_TOT];            // 192
    float* psis = &sm[F1_TOT + 192];      // [16][256]

    const int nw = (d + 15) >> 4;
    for (int w = 0; w < nw; ++w) {
      const int b0 = w * 16;
      __syncthreads();
      if (t < 192) {
        const int s = t / 12, f = t % 12;
        sphi[t] = (b0 + s < d) ? phi[(size_t)(off0 + b0 + s)*12 + f] : 0.f;
      }
      __syncthreads();

      {
        float z[8][1];
        zcompute<128,128,1>(Pt + OFF_000, xa, o, z);
#pragma unroll
        for (int e = 0; e < 16; ++e)
          psis[e*256 + t] = kdot<1>(z, 0, &sphi[e*12]);
      }
      {
        float z[8][3];
        zcompute<128,96,3>(Pt + OFF_110, xv, o, z);
#pragma unroll
        for (int e = 0; e < 16; ++e) {
          const float* ph = &sphi[e*12];
          psis[e*256 + t] += ph[8]*kdot<3>(z,0,ph) + ph[9]*kdot<3>(z,1,ph) + ph[10]*kdot<3>(z,2,ph);
        }
      }
#pragma unroll
      for (int kh = 0; kh < 2; ++kh) {
        float z[4][9];
        zcompute_k4n<128,64,9>(Pt + OFF_220, xd, o, kh, z);
#pragma unroll
        for (int e = 0; e < 16; ++e) {
          const float* ph = &sphi[e*12];
          const float* rr = ph + kh*4;
          float s[9];
#pragma unroll
          for (int m = 0; m < 9; ++m) s[m] = kdot4n<9>(z, m, rr);
          const float q0 = ph[8], q1 = ph[9], q2 = ph[10];
          psis[e*256 + t] += q0*(q0*s[0] + q1*s[1] + q2*s[2])
                           + q1*(q0*s[3] + q1*s[4] + q2*s[5])
                           + q2*(q0*s[6] + q1*s[7] + q2*s[8]);
        }
      }
#pragma unroll
      for (int e = 0; e < 16; ++e)
        if (b0 + e < d) psiA[(size_t)(off0 + b0 + e)*256 + t] = f2bf(psis[e*256 + t]);
    }
  } else if (type == 1) {
    // ---------------- pass V: 192 active thr, window 14 ----------------
    const bool act = (t < 192);
    const int o = t % 96, l = (t / 96) & 1;   // clamped for surplus lanes
    const float* xa = &sm[F1_XA + l*128];
    const float* xv = &sm[F1_XV + l*288];
    const float* xd = &sm[F1_XD + l*576];
    float* sphi = &sm[F1_TOT];            // 168
    float* psis = &sm[F1_TOT + 168];      // [14][3][192]

    const int nw = (d + 13) / 14;
    for (int w = 0; w < nw; ++w) {
      const int b0 = w * 14;
      __syncthreads();
      if (t < 168) {
        const int s = t / 12, f = t % 12;
        sphi[t] = (b0 + s < d) ? phi[(size_t)(off0 + b0 + s)*12 + f] : 0.f;
      }
      __syncthreads();

      if (act) {
        {
          float z[8][3];
          zcompute<96,96,3>(Pt + OFF_011, xv, o, z);
#pragma unroll
          for (int e = 0; e < 14; ++e) {
            const float* ph = &sphi[e*12];
            float* pb = &psis[e*576 + t];
            pb[0]   = kdot<3>(z,0,ph);
            pb[192] = kdot<3>(z,1,ph);
            pb[384] = kdot<3>(z,2,ph);
          }
        }
        {
          float z[8][1];
          zcompute<96,128,1>(Pt + OFF_101, xa, o, z);
#pragma unroll
          for (int e = 0; e < 14; ++e) {
            const float* ph = &sphi[e*12];
            const float s0 = kdot<1>(z,0,ph);
            float* pb = &psis[e*576 + t];
            pb[0] += ph[8]*s0; pb[192] += ph[9]*s0; pb[384] += ph[10]*s0;
          }
        }
#pragma unroll
        for (int kh = 0; kh < 2; ++kh) {
          float z[4][9];
          zcompute_k4n<96,64,9>(Pt + OFF_121, xd, o, kh, z);
#pragma unroll
          for (int e = 0; e < 14; ++e) {
            const float* ph = &sphi[e*12];
            const float* rr = ph + kh*4;
            float s[9];
#pragma unroll
            for (int m = 0; m < 9; ++m) s[m] = kdot4n<9>(z, m, rr);
            const float q0 = ph[8], q1 = ph[9], q2 = ph[10];
            float* pb = &psis[e*576 + t];
            pb[0]   += q0*s[0] + q1*s[1] + q2*s[2];
            pb[192] += q0*s[3] + q1*s[4] + q2*s[5];
            pb[384] += q0*s[6] + q1*s[7] + q2*s[8];
          }
        }
        {
          float z[8][3];
          zcompute<96,96,3>(Pt + OFF_211, xv, o, z);
#pragma unroll
          for (int e = 0; e < 14; ++e) {
            const float* ph = &sphi[e*12];
            const float tt = ph[8]*kdot<3>(z,0,ph) + ph[9]*kdot<3>(z,1,ph) + ph[10]*kdot<3>(z,2,ph);
            float* pb = &psis[e*576 + t];
            pb[0] += ph[8]*tt; pb[192] += ph[9]*tt; pb[384] += ph[10]*tt;
          }
        }
        {
          float z[8][3];
          zcompute<96,96,3>(Pt + OFF_111, xv, o, z);
#pragma unroll
          for (int e = 0; e < 14; ++e) {
            const float* ph = &sphi[e*12];
            const float s0 = kdot<3>(z,0,ph), s1 = kdot<3>(z,1,ph), s2 = kdot<3>(z,2,ph);
            const float q0 = ph[8], q1 = ph[9], q2 = ph[10];
            float* pb = &psis[e*576 + t];
            pb[0]   += q1*s2 - q2*s1;
            pb[192] += q2*s0 - q0*s2;
            pb[384] += q0*s1 - q1*s0;
          }
        }
#pragma unroll
        for (int e = 0; e < 14; ++e) {
          if (b0 + e < d) {
            const size_t bb = (size_t)(off0 + b0 + e)*576 + l*288 + o*3;
            const float* pb = &psis[e*576 + t];
            psiV[bb+0] = f2bf(pb[0]); psiV[bb+1] = f2bf(pb[192]); psiV[bb+2] = f2bf(pb[384]);
          }
        }
      }
    }
  } else {
    // ---------------- pass D: 128 active thr, window 7 ----------------
    const bool act = (t < 128);
    const int o = t & 63, l = (t >> 6) & 1;   // clamped for surplus lanes
    const float* xa = &sm[F1_XA + l*128];
    const float* xv = &sm[F1_XV + l*288];
    const float* xd = &sm[F1_XD + l*576];
    float* sphi = &sm[F1_TOT];            // 84
    float* psis = &sm[F1_TOT + 84];       // [7][128][9]

    const int nw = (d + 6) / 7;
    for (int w = 0; w < nw; ++w) {
      const int b0 = w * 7;
      __syncthreads();
      if (t < 84) {
        const int s = t / 12, f = t % 12;
        sphi[t] = (b0 + s < d) ? phi[(size_t)(off0 + b0 + s)*12 + f] : 0.f;
      }
      __syncthreads();

      if (act) {
        {
          float z[4][9];
          zcompute_k4n<64,64,9>(Pt + OFF_022, xd, o, 0, z);
#pragma unroll
          for (int e = 0; e < 7; ++e) {
            const float* rr = &sphi[e*12];
            float* pb = &psis[(e*128 + t)*9];
#pragma unroll
            for (int m = 0; m < 9; ++m) pb[m] = kdot4n<9>(z, m, rr);
          }
        }
        {
          float z[4][9];
          zcompute_k4n<64,64,9>(Pt + OFF_022, xd, o, 1, z);
#pragma unroll
          for (int e = 0; e < 7; ++e) {
            const float* rr = &sphi[e*12] + 4;
            float* pb = &psis[(e*128 + t)*9];
#pragma unroll
            for (int m = 0; m < 9; ++m) pb[m] += kdot4n<9>(z, m, rr);
          }
        }
        {
          float z[8][1];
          zcompute<64,128,1>(Pt + OFF_202, xa, o, z);
#pragma unroll
          for (int e = 0; e < 7; ++e) {
            const float* ph = &sphi[e*12];
            const float s0 = kdot<1>(z, 0, ph);
            const float q0 = ph[8], q1 = ph[9], q2 = ph[10];
            float* pb = &psis[(e*128 + t)*9];
            pb[0] += q0*q0*s0; pb[1] += q0*q1*s0; pb[2] += q0*q2*s0;
            pb[3] += q1*q0*s0; pb[4] += q1*q1*s0; pb[5] += q1*q2*s0;
            pb[6] += q2*q0*s0; pb[7] += q2*q1*s0; pb[8] += q2*q2*s0;
          }
        }
        {
          float z[8][3];
          zcompute<64,96,3>(Pt + OFF_112, xv, o, z);
#pragma unroll
          for (int e = 0; e < 7; ++e) {
            const float* ph = &sphi[e*12];
            const float s0 = kdot<3>(z,0,ph), s1 = kdot<3>(z,1,ph), s2 = kdot<3>(z,2,ph);
            const float q0 = ph[8], q1 = ph[9], q2 = ph[10];
            float* pb = &psis[(e*128 + t)*9];
            pb[0] += q0*s0; pb[1] += q0*s1; pb[2] += q0*s2;
            pb[3] += q1*s0; pb[4] += q1*s1; pb[5] += q1*s2;
            pb[6] += q2*s0; pb[7] += q2*s1; pb[8] += q2*s2;
          }
        }
#pragma unroll
        for (int kh = 0; kh < 2; ++kh) {
          float z[4][9];
          zcompute_k4n<64,64,9>(Pt + OFF_222, xd, o, kh, z);
#pragma unroll
          for (int e = 0; e < 7; ++e) {
            const float* ph = &sphi[e*12];
            const float* rr = ph + kh*4;
            float s[9];
#pragma unroll
            for (int m = 0; m < 9; ++m) s[m] = kdot4n<9>(z, m, rr);
            const float q0 = ph[8], q1 = ph[9], q2 = ph[10];
            const float u0 = q0*s[0] + q1*s[3] + q2*s[6];
            const float u1 = q0*s[1] + q1*s[4] + q2*s[7];
            const float u2 = q0*s[2] + q1*s[5] + q2*s[8];
            float* pb = &psis[(e*128 + t)*9];
            pb[0] += q0*u0; pb[1] += q0*u1; pb[2] += q0*u2;
            pb[3] += q1*u0; pb[4] += q1*u1; pb[5] += q1*u2;
            pb[6] += q2*u0; pb[7] += q2*u1; pb[8] += q2*u2;
          }
        }
        {
          float z[8][3];
          zcompute<64,96,3>(Pt + OFF_212, xv, o, z);
#pragma unroll
          for (int e = 0; e < 7; ++e) {
            const float* ph = &sphi[e*12];
            const float s0 = kdot<3>(z,0,ph), s1 = kdot<3>(z,1,ph), s2 = kdot<3>(z,2,ph);
            const float q0 = ph[8], q1 = ph[9], q2 = ph[10];
            const float c0 = q1*s2 - q2*s1;
            const float c1 = q2*s0 - q0*s2;
            const float c2 = q0*s1 - q1*s0;
            float* pb = &psis[(e*128 + t)*9];
            pb[0] += c0*q0; pb[1] += c0*q1; pb[2] += c0*q2;
            pb[3] += c1*q0; pb[4] += c1*q1; pb[5] += c1*q2;
            pb[6] += c2*q0; pb[7] += c2*q1; pb[8] += c2*q2;
          }
        }
#pragma unroll
        for (int e = 0; e < 7; ++e) {
          if (b0 + e < d) {
            const float* pb = &psis[(e*128 + t)*9];
            unsigned short* bp = &psiD[(size_t)(off0 + b0 + e)*1152 + t*9];
#pragma unroll
            for (int j = 0; j < 9; ++j) bp[j] = f2bf(pb[j]);
          }
        }
      }
    }
  }
}

// ---------------------------------------------------------------------------
// FUSED edge MLPs: grid 15000, 256 thr.  b%3==0 -> mlp_a (5000 blocks,
// 16 combos); else -> mlp_v (10000 blocks, 8 combos, 192 active thr).
// NO early returns: barriers at block scope, work guarded by `act`.
// ---------------------------------------------------------------------------
__global__ __launch_bounds__(256, 3) void mlp_fused_kernel(
    unsigned short* __restrict__ psiA, unsigned short* __restrict__ psiV,
    const float* __restrict__ Wdt,
    const float* __restrict__ W1t, const float* __restrict__ b1,
    const float* __restrict__ W2t, const float* __restrict__ b2,
    const float* __restrict__ W3t, const float* __restrict__ b3,
    const float* __restrict__ Vdt, const float* __restrict__ V1t,
    const float* __restrict__ V2t, const float* __restrict__ V3t)
{
  __shared__ float sm[11520];   // max(a:10240, v:11520) floats = 46080 B
  const int b = blockIdx.x;
  const int t = threadIdx.x;

  if (b % 3 == 0) {
    // ---------------- mlp_a: 16 combos ----------------
    const int cbase = (b / 3) * 16;
    float* PA = sm;            // [16][128]
    float* H1 = sm + 2048;     // [16][256]
    float* H2 = sm + 6144;     // [16][256]

    for (int q = t; q < 2048; q += 256)
      PA[q] = bf2f(psiA[(size_t)cbase*128 + q]);
    __syncthreads();
    {
      const int p0 = (t & 63) * 4, j0 = (t >> 6) * 4;
      float acc[4][4];
#pragma unroll
      for (int r = 0; r < 4; ++r)
#pragma unroll
        for (int j = 0; j < 4; ++j) acc[r][j] = 0.f;
      for (int c = 0; c < 128; c += 4) {
        float4 wv[4];
#pragma unroll
        for (int cc = 0; cc < 4; ++cc) wv[cc] = *(const float4*)&W1t[(size_t)(c+cc)*256 + p0];
#pragma unroll
        for (int j = 0; j < 4; ++j) {
          const float4 x = *(const float4*)&PA[(j0+j)*128 + c];
          acc[0][j] += wv[0].x*x.x + wv[1].x*x.y + wv[2].x*x.z + wv[3].x*x.w;
          acc[1][j] += wv[0].y*x.x + wv[1].y*x.y + wv[2].y*x.z + wv[3].y*x.w;
          acc[2][j] += wv[0].z*x.x + wv[1].z*x.y + wv[2].z*x.z + wv[3].z*x.w;
          acc[3][j] += wv[0].w*x.x + wv[1].w*x.y + wv[2].w*x.z + wv[3].w*x.w;
        }
      }
      const float bb0 = b1[p0], bb1 = b1[p0+1], bb2 = b1[p0+2], bb3 = b1[p0+3];
#pragma unroll
      for (int j = 0; j < 4; ++j) {
        float4 v; v.x = lrelu(acc[0][j]+bb0); v.y = lrelu(acc[1][j]+bb1);
        v.z = lrelu(acc[2][j]+bb2); v.w = lrelu(acc[3][j]+bb3);
        *(float4*)&H1[(j0+j)*256 + p0] = v;
      }
    }
    __syncthreads();
    {
      const int p0 = (t & 63) * 4, j0 = (t >> 6) * 4;
      float acc[4][4];
#pragma unroll
      for (int r = 0; r < 4; ++r)
#pragma unroll
        for (int j = 0; j < 4; ++j) acc[r][j] = 0.f;
      for (int c = 0; c < 256; c += 4) {
        float4 wv[4];
#pragma unroll
        for (int cc = 0; cc < 4; ++cc) wv[cc] = *(const float4*)&W2t[(size_t)(c+cc)*256 + p0];
#pragma unroll
        for (int j = 0; j < 4; ++j) {
          const float4 x = *(const float4*)&H1[(j0+j)*256 + c];
          acc[0][j] += wv[0].x*x.x + wv[1].x*x.y + wv[2].x*x.z + wv[3].x*x.w;
          acc[1][j] += wv[0].y*x.x + wv[1].y*x.y + wv[2].y*x.z + wv[3].y*x.w;
          acc[2][j] += wv[0].z*x.x + wv[1].z*x.y + wv[2].z*x.z + wv[3].z*x.w;
          acc[3][j] += wv[0].w*x.x + wv[1].w*x.y + wv[2].w*x.z + wv[3].w*x.w;
        }
      }
      const float bb0 = b2[p0], bb1 = b2[p0+1], bb2 = b2[p0+2], bb3 = b2[p0+3];
#pragma unroll
      for (int j = 0; j < 4; ++j) {
        float4 v; v.x = lrelu(acc[0][j]+bb0); v.y = lrelu(acc[1][j]+bb1);
        v.z = lrelu(acc[2][j]+bb2); v.w = lrelu(acc[3][j]+bb3);
        *(float4*)&H2[(j0+j)*256 + p0] = v;
      }
    }
    __syncthreads();
    {
      const int p0 = (t & 63) * 2, j0 = (t >> 6) * 4;
      float acc[2][4];
#pragma unroll
      for (int r = 0; r < 2; ++r)
#pragma unroll
        for (int j = 0; j < 4; ++j) acc[r][j] = 0.f;
      for (int c = 0; c < 128; c += 4) {
        float2 wv[4];
#pragma unroll
        for (int cc = 0; cc < 4; ++cc) wv[cc] = *(const float2*)&Wdt[(size_t)(c+cc)*128 + p0];
#pragma unroll
        for (int j = 0; j < 4; ++j) {
          const float4 x = *(const float4*)&PA[(j0+j)*128 + c];
          acc[0][j] += wv[0].x*x.x + wv[1].x*x.y + wv[2].x*x.z + wv[3].x*x.w;
          acc[1][j] += wv[0].y*x.x + wv[1].y*x.y + wv[2].y*x.z + wv[3].y*x.w;
        }
      }
      for (int c = 0; c < 256; c += 4) {
        float2 wv[4];
#pragma unroll
        for (int cc = 0; cc < 4; ++cc) wv[cc] = *(const float2*)&W3t[(size_t)(c+cc)*128 + p0];
#pragma unroll
        for (int j = 0; j < 4; ++j) {
          const float4 x = *(const float4*)&H2[(j0+j)*256 + c];
          acc[0][j] += wv[0].x*x.x + wv[1].x*x.y + wv[2].x*x.z + wv[3].x*x.w;
          acc[1][j] += wv[0].y*x.x + wv[1].y*x.y + wv[2].y*x.z + wv[3].y*x.w;
        }
      }
      const float bb0 = b3[p0], bb1 = b3[p0+1];
#pragma unroll
      for (int j = 0; j < 4; ++j) {
        const float o0 = acc[0][j] + bb0 + PA[(j0+j)*128 + p0];
        const float o1 = acc[1][j] + bb1 + PA[(j0+j)*128 + p0 + 1];
        psiA[(size_t)(cbase + j0 + j)*128 + p0]     = f2bf(o0);
        psiA[(size_t)(cbase + j0 + j)*128 + p0 + 1] = f2bf(o1);
      }
    }
  } else {
    // ---------------- mlp_v: 8 combos, 192 active thr ----------------
    const bool act = (t < 192);
    const int cbase = (b - b/3 - 1) * 8;
    float* PV  = sm;            // [8][288]
    float* HV  = sm + 2304;     // [8][576]
    float* HV2 = sm + 6912;     // [8][576]

    for (int q = t; q < 2304; q += 256) {   // all 256 threads stage
      const int j = q / 288, r = q % 288, i = r / 96, o = r % 96;
      PV[j*288 + i*96 + o] = bf2f(psiV[(size_t)(cbase + j)*288 + o*3 + i]);
    }
    __syncthreads();
    if (act) {
      const int p0 = (t % 96) * 2, j0 = (t / 96) * 4;
      float acc[2][4][3];
#pragma unroll
      for (int r = 0; r < 2; ++r)
#pragma unroll
        for (int j = 0; j < 4; ++j) { acc[r][j][0]=0.f; acc[r][j][1]=0.f; acc[r][j][2]=0.f; }
      for (int c = 0; c < 96; c += 4) {
        float2 wv[4];
#pragma unroll
        for (int cc = 0; cc < 4; ++cc) wv[cc] = *(const float2*)&V1t[(size_t)(c+cc)*192 + p0];
#pragma unroll
        for (int j = 0; j < 4; ++j)
#pragma unroll
          for (int i = 0; i < 3; ++i) {
            const float4 x = *(const float4*)&PV[(j0+j)*288 + i*96 + c];
            acc[0][j][i] += wv[0].x*x.x + wv[1].x*x.y + wv[2].x*x.z + wv[3].x*x.w;
            acc[1][j][i] += wv[0].y*x.x + wv[1].y*x.y + wv[2].y*x.z + wv[3].y*x.w;
          }
      }
      float scl[2][4];
#pragma unroll
      for (int r = 0; r < 2; ++r)
#pragma unroll
        for (int j = 0; j < 4; ++j) {
          const float nn = sqrtf(acc[r][j][0]*acc[r][j][0] + acc[r][j][1]*acc[r][j][1]
                               + acc[r][j][2]*acc[r][j][2] + 1e-12f);
          scl[r][j] = (2.f / (1.f + expf(-nn)) - 1.f) / nn;
        }
#pragma unroll
      for (int j = 0; j < 4; ++j)
#pragma unroll
        for (int i = 0; i < 3; ++i) {
          float2 v;
          v.x = acc[0][j][i]*scl[0][j]; v.y = acc[1][j][i]*scl[1][j];
          *(float2*)&HV[(j0+j)*576 + i*192 + p0] = v;
        }
    }
    __syncthreads();
    if (act) {
      const int p0 = (t % 96) * 2, j0 = (t / 96) * 4;
      float acc[2][4][3];
#pragma unroll
      for (int r = 0; r < 2; ++r)
#pragma unroll
        for (int j = 0; j < 4; ++j) { acc[r][j][0]=0.f; acc[r][j][1]=0.f; acc[r][j][2]=0.f; }
      for (int c = 0; c < 192; c += 4) {
        float2 wv[4];
#pragma unroll
        for (int cc = 0; cc < 4; ++cc) wv[cc] = *(const float2*)&V2t[(size_t)(c+cc)*192 + p0];
#pragma unroll
        for (int j = 0; j < 4; ++j)
#pragma unroll
          for (int i = 0; i < 3; ++i) {
            const float4 x = *(const float4*)&HV[(j0+j)*576 + i*192 + c];
            acc[0][j][i] += wv[0].x*x.x + wv[1].x*x.y + wv[2].x*x.z + wv[3].x*x.w;
            acc[1][j][i] += wv[0].y*x.x + wv[1].y*x.y + wv[2].y*x.z + wv[3].y*x.w;
          }
      }
      float scl[2][4];
#pragma unroll
      for (int r = 0; r < 2; ++r)
#pragma unroll
        for (int j = 0; j < 4; ++j) {
          const float nn = sqrtf(acc[r][j][0]*acc[r][j][0] + acc[r][j][1]*acc[r][j][1]
                               + acc[r][j][2]*acc[r][j][2] + 1e-12f);
          scl[r][j] = (2.f / (1.f + expf(-nn)) - 1.f) / nn;
        }
#pragma unroll
      for (int j = 0; j < 4; ++j)
#pragma unroll
        for (int i = 0; i < 3; ++i) {
          float2 v;
          v.x = acc[0][j][i]*scl[0][j]; v.y = acc[1][j][i]*scl[1][j];
          *(float2*)&HV2[(j0+j)*576 + i*192 + p0] = v;
        }
    }
    __syncthreads();
    if (act) {
      const int p0 = t % 96, j0 = (t / 96) * 4;
      float acc[4][3];
#pragma unroll
      for (int j = 0; j < 4; ++j) { acc[j][0]=0.f; acc[j][1]=0.f; acc[j][2]=0.f; }
      for (int c = 0; c < 96; c += 4) {
        float wv[4];
#pragma unroll
        for (int cc = 0; cc < 4; ++cc) wv[cc] = Vdt[(size_t)(c+cc)*96 + p0];
#pragma unroll
        for (int j = 0; j < 4; ++j)
#pragma unroll
          for (int i = 0; i < 3; ++i) {
            const float4 x = *(const float4*)&PV[(j0+j)*288 + i*96 + c];
            acc[j][i] += wv[0]*x.x + wv[1]*x.y + wv[2]*x.z + wv[3]*x.w;
          }
      }
      for (int c = 0; c < 192; c += 4) {
        float wv[4];
#pragma unroll
        for (int cc = 0; cc < 4; ++cc) wv[cc] = V3t[(size_t)(c+cc)*96 + p0];
#pragma unroll
        for (int j = 0; j < 4; ++j)
#pragma unroll
          for (int i = 0; i < 3; ++i) {
            const float4 x = *(const float4*)&HV2[(j0+j)*576 + i*192 + c];
            acc[j][i] += wv[0]*x.x + wv[1]*x.y + wv[2]*x.z + wv[3]*x.w;
          }
      }
#pragma unroll
      for (int j = 0; j < 4; ++j)
#pragma unroll
        for (int i = 0; i < 3; ++i) {
          const float v = acc[j][i] + PV[(j0+j)*288 + i*96 + p0];
          psiV[(size_t)(cbase + j0 + j)*288 + p0*3 + i] = f2bf(v);
        }
    }
  }
}

// ---------------------------------------------------------------------------
// Gather (by src) + fused output projection. Block per src atom, 256 thr.
// ---------------------------------------------------------------------------
__global__ __launch_bounds__(256, 2) void gather_out_kernel(
    const int* __restrict__ soff, const int* __restrict__ sperm,
    const unsigned short* __restrict__ psiA, const unsigned short* __restrict__ psiV,
    const unsigned short* __restrict__ psiD,
    const float* __restrict__ Wa, const float* __restrict__ Wv, const float* __restrict__ Wd,
    float* __restrict__ out)
{
  __shared__ float bs[1984];
  const int n = blockIdx.x, t = threadIdx.x;
  const int s0 = soff[n], s1 = soff[n + 1];
  float acc[8];
#pragma unroll
  for (int u = 0; u < 8; ++u) acc[u] = 0.f;
  for (int p2 = s0; p2 < s1; ++p2) {
    const int slot = sperm[p2];
    const unsigned short* ra = psiA + (size_t)slot * 256;
    const unsigned short* rv = psiV + (size_t)slot * 576;
    const unsigned short* rd = psiD + (size_t)slot * 1152;
#pragma unroll
    for (int u = 0; u < 8; ++u) {
      const int v = t + 256 * u;
      if (v < 256)        acc[u] += bf2f(ra[v]);
      else if (v < 832)   acc[u] += bf2f(rv[v - 256]);
      else if (v < 1984)  acc[u] += bf2f(rd[v - 832]);
    }
  }
#pragma unroll
  for (int u = 0; u < 8; ++u) {
    const int v = t + 256 * u;
    if (v < 1984) bs[v] = acc[u];
  }
  __syncthreads();
  if (t < 128) {
    const float* W = &Wa[(size_t)t * 256];
    float a = 0.f;
    for (int c = 0; c < 256; c += 4) a += dot4f(*(const float4*)&W[c], *(const float4*)&bs[c]);
    out[(size_t)n*128 + t] = a;
  }
  if (t < 96) {
    const float* W = &Wv[(size_t)t * 192];
    float a0 = 0.f, a1 = 0.f, a2 = 0.f;
    for (int c = 0; c < 192; ++c) {
      const float w = W[c]; const float* x = &bs[256 + c*3];
      a0 = fmaf(w, x[0], a0); a1 = fmaf(w, x[1], a1); a2 = fmaf(w, x[2], a2);
    }
    float* d = &out[OUT_V + ((size_t)n*96 + t)*3];
    d[0] = a0; d[1] = a1; d[2] = a2;
  }
  if (t < 64) {
    const float* W = &Wd[(size_t)t * 128];
    float a[9] = {0,0,0,0,0,0,0,0,0};
    for (int c = 0; c < 128; ++c) {
      const float w = W[c]; const float* x = &bs[832 + c*9];
#pragma unroll
      for (int j = 0; j < 9; ++j) a[j] = fmaf(w, x[j], a[j]);
    }
    float* d = &out[OUT_D + ((size_t)n*64 + t)*9];
#pragma unroll
    for (int j = 0; j < 9; ++j) d[j] = a[j];
  }
}

// ---------------------------------------------------------------------------
// Host entry
// ---------------------------------------------------------------------------
extern "C" void kernel_launch(void* const* d_in, const int* in_sizes, int n_in,
                              void* d_out, int out_size, void* d_ws, size_t ws_size,
                              hipStream_t stream) {
  (void)in_sizes; (void)n_in; (void)out_size; (void)ws_size;
  const int*   src  = (const int*)d_in[0];
  const int*   dst  = (const int*)d_in[1];
  const float* r_ij = (const float*)d_in[2];
  const float* x_a  = (const float*)d_in[3];
  const float* x_v  = (const float*)d_in[4];
  const float* x_d  = (const float*)d_in[5];
  const float* P[13];
  for (int i = 0; i < 13; ++i) P[i] = (const float*)d_in[6 + i];
  const float* W_in_a  = (const float*)d_in[19];
  const float* W_in_v  = (const float*)d_in[20];
  const float* W_in_d  = (const float*)d_in[21];
  const float* W_out_a = (const float*)d_in[22];
  const float* W_out_v = (const float*)d_in[23];
  const float* W_out_d = (const float*)d_in[24];
  const float* Wd_a = (const float*)d_in[25];
  const float* W1   = (const float*)d_in[26];
  const float* b1   = (const float*)d_in[27];
  const float* W2   = (const float*)d_in[28];
  const float* b2   = (const float*)d_in[29];
  const float* W3   = (const float*)d_in[30];
  const float* b3   = (const float*)d_in[31];
  const float* Vd   = (const float*)d_in[32];
  const float* V1   = (const float*)d_in[33];
  const float* V2   = (const float*)d_in[34];
  const float* V3   = (const float*)d_in[35];

  float* ws = (float*)d_ws;
  float* Pt = ws;
  int*   ib = (int*)(ws + INT_OFF);
  unsigned short* psiA = (unsigned short*)(ws + PSIA_OFF);
  unsigned short* psiV = (unsigned short*)(ws + PSIV_OFF);
  unsigned short* psiD = (unsigned short*)(ws + PSID_OFF);
  float* ot = (float*)d_out;   // head of d_out = transposed-weight scratch

  // 1) fused transposes (2 launches instead of 21)
  P13 ps; for (int i = 0; i < 13; ++i) ps.p[i] = P[i];
  transP_all_kernel<<<(111616 + 255) / 256, 256, 0, stream>>>(ps, Pt);
  P8 pw;
  pw.p[0] = W1; pw.p[1] = W2; pw.p[2] = W3; pw.p[3] = Wd_a;
  pw.p[4] = V1; pw.p[5] = V2; pw.p[6] = V3; pw.p[7] = Vd;
  transW_all_kernel<<<(230400 + 255) / 256, 256, 0, stream>>>(pw, ot);

  // 2) zero sort counters
  hipMemsetAsync(ib, 0, 20000 * sizeof(int), stream);

  // 3) sorts + per-edge encodings (4 launches)
  const int egrid = (NE + 255) / 256;
  hist2_kernel<<<egrid, 256, 0, stream>>>(dst, src, ib + ICNT, ib + SCNT);
  scan2_kernel<<<2, 256, 0, stream>>>(ib + ICNT, ib + IOFF, ib + SCNT, ib + SOFF);
  sort_scatter_kernel<<<egrid, 256, 0, stream>>>(dst, ib + IOFF, ib + ICUR, ib + IEIDX, ib + ISLOT);
  ssort_phi_kernel<<<2 * egrid, 256, 0, stream>>>(src, ib + ISLOT, ib + SOFF, ib + SCUR,
                                                  ib + SPERM, ib + IEIDX, r_ij, ws + PHI_OFF);

  // 4) input projections
  proj_in_kernel<<<NA, 256, 0, stream>>>(x_a, x_v, x_d, W_in_a, W_in_v, W_in_d,
                                         ws + A_OFF, ws + V_OFF, ws + D_OFF);

  // 5) FUSED message passes: a/v/d blocks co-resident (type = blockIdx%3)
  pass_fused_kernel<<<3 * NA, 256, 0, stream>>>(ib + IOFF, ws + PHI_OFF, Pt,
                                                ws + A_OFF, ws + V_OFF, ws + D_OFF,
                                                psiA, psiV, psiD);

  // 6) FUSED edge MLPs (a: 5000 blocks, v: 10000 blocks)
  mlp_fused_kernel<<<15000, 256, 0, stream>>>(psiA, psiV,
                                              ot + WTD, ot + WT1, b1, ot + WT2, b2, ot + WT3, b3,
                                              ot + VTD, ot + VT1, ot + VT2, ot + VT3);

  // 7) gather by src + fused output projection (overwrites all of d_out)
  gather_out_kernel<<<NA, 256, 0, stream>>>(ib + SOFF, ib + SPERM,
                                            psiA, psiV, psiD,
                                            W_out_a, W_out_v, W_out_d, (float*)d_out);
}